// Round 12
// baseline (308.526 us; speedup 1.0000x reference)
//
#include <hip/hip_runtime.h>
#include <hip/hip_bf16.h>
#include <math.h>

// ---------------------------------------------------------------------------
// MjCambrianOptics. Correctness-critical (R7-validated, DO NOT TOUCH):
//   * mean(depth) = numpy BUFFERED reduce: seed a[0], then sequential
//     += pairwise_sum(8192-chunk), 128-leaf/8-acc recursion.
//   * ki = fl32(2pi)/fl32(wl) f32 divide; linspace f64-cast; th/ph op order.
// R11: conv -> MFMA (banded-Toeplitz implicit GEMM, split-bf16 hi/lo).
// R15: sched_barrier-pinned one-dloc-ahead A prefetch.
// R17: sliding-window P4 => coalesced A-loads. 162->82 us (CONFIRMED).
// R18: two j-tiles/block (A reuse). 82->55.6.
// R19: FAILED (256,4) VGPR cap -> spill. 2 blocks/CU is a HARD constraint.
// R20: (256,2) + 16x32 cgemm 128-blocks/plane. tot 252.7 (best).
// R21: DOUBLE REGRESSION, both reverted: (a) LDS swizzle killed conflicts
//      5.8M->283K but k_conv got SLOWER (conflicts were hidden; XOR math
//      was not) -> conflicts are NOT on the critical path. (b) 128-thread
//      2x2 cgemm cost ~+33 us (halved latency-hiding waves/block).
// R22: R20-exact + cgemm BK=32 (As[16][33], Bs[32][33]): halves the
//      32-barriers/block overhead. k order still 0..255 sequential per
//      output -> bit-identical.  [R23: resubmit — R11 bench was an infra
//      failure ("container failed twice"), kernel audited sound.]
// ---------------------------------------------------------------------------

constexpr int M   = 255;
constexpr int NP  = M * M;        // 65025
constexpr int RESO = 160;

// IMG2 (padded bf16 image, hi|lo): [side][ch][row 0..415][col 0..447]
constexpr int IMG_ROWS = 416, IMG_COLS = 448;
constexpr int IMG_CH   = IMG_ROWS * IMG_COLS;      // 186368
constexpr int IMG_SIDE = 3 * IMG_CH;               // 559104
// P4 sliding-window table (bf16 hi|lo): [side][ch][di 0..255][u 0..303][t 0..7]
// entry (di,u,t) = psf[di][u-16+t], zero-padded outside [0,M)
constexpr int P4_DI   = 304 * 8;                   // 2432 shorts per di
constexpr int P4_CH   = 256 * P4_DI;               // 622592
constexpr int P4_SIDE = 3 * P4_CH;                 // 1867776

typedef __attribute__((ext_vector_type(8))) short short8;
typedef __attribute__((ext_vector_type(4))) float f32x4;

__device__ __forceinline__ unsigned short f2bf(float f) {
    unsigned int u = __float_as_uint(f);
    unsigned int r = (u + 0x7fffu + ((u >> 16) & 1u)) >> 16;
    return (unsigned short)r;
}
__device__ __forceinline__ float bf2f(unsigned short h) {
    return __uint_as_float(((unsigned int)h) << 16);
}

// ---------------- numpy buffered-reduce pairwise forest (compile-time) ------
constexpr int MAXN = 1100;
struct PWForest {
    int kind[MAXN];
    int off[MAXN], len[MAXN];
    int li[MAXN], ri[MAXN];
    int lvl[MAXN];
    int nNode, nLeaf, maxLvl;
    int roots[16], nRoots;
};
constexpr int pwf_build(PWForest& T, int o, int n) {
    if (n <= 128) {
        int id = T.nNode++;
        T.kind[id] = 0; T.off[id] = o; T.len[id] = n;
        T.lvl[id] = 0; T.nLeaf++;
        return id;
    }
    int n2 = (n / 2) - ((n / 2) % 8);
    int a = pwf_build(T, o, n2);
    int b = pwf_build(T, o + n2, n - n2);
    int id = T.nNode++;
    T.kind[id] = 1; T.li[id] = a; T.ri[id] = b;
    int l = (T.lvl[a] > T.lvl[b] ? T.lvl[a] : T.lvl[b]) + 1;
    T.lvl[id] = l; if (l > T.maxLvl) T.maxLvl = l;
    return id;
}
constexpr PWForest pwf_make() {
    PWForest T{};
    int pos = 1, rem = NP - 1;            // reduce seeds with a[0]
    while (rem > 0) {
        int c = rem > 8192 ? 8192 : rem;  // nditer buffer = 8192 elements
        T.roots[T.nRoots++] = pwf_build(T, pos, c);
        pos += c; rem -= c;
    }
    return T;
}
constexpr PWForest PW = pwf_make();
static_assert(PW.nNode <= MAXN, "forest overflow");
static_assert(PW.nRoots == 8, "chunk count");

// leaves are independent: one THREAD per node id, exact per-leaf arithmetic
__global__ void k_mleaf(const float* __restrict__ depth, float* __restrict__ val) {
    int id = blockIdx.x * 256 + threadIdx.x;
    if (id >= PW.nNode || PW.kind[id] != 0) return;
    const float* a = depth + PW.off[id];
    int n = PW.len[id];
    float r0 = a[0], r1 = a[1], r2 = a[2], r3 = a[3];
    float r4 = a[4], r5 = a[5], r6 = a[6], r7 = a[7];
    int lim = n - (n % 8);
    int i = 8;
    for (; i < lim; i += 8) {
        r0 += a[i + 0]; r1 += a[i + 1]; r2 += a[i + 2]; r3 += a[i + 3];
        r4 += a[i + 4]; r5 += a[i + 5]; r6 += a[i + 6]; r7 += a[i + 7];
    }
    float res = ((r0 + r1) + (r2 + r3)) + ((r4 + r5) + (r6 + r7));
    for (; i < n; ++i) res += a[i];
    val[id] = res;
}

// internal levels + root chain, single block (exact same order as before)
__global__ void k_mtree(const float* __restrict__ depth, float* __restrict__ val,
                        float* __restrict__ meanp) {
    int tid = threadIdx.x;
    for (int l = 1; l <= PW.maxLvl; ++l) {
        for (int id = tid; id < PW.nNode; id += 256)
            if (PW.kind[id] == 1 && PW.lvl[id] == l)
                val[id] = val[PW.li[id]] + val[PW.ri[id]];
        __syncthreads();
    }
    if (tid == 0) {
        float io1 = depth[0];
        for (int r = 0; r < PW.nRoots; ++r)
            io1 = io1 + val[PW.roots[r]];
        meanp[0] = io1 / 65025.0f;
    }
}

// ---------------- prep: u2H fields + DFT W + padded bf16 image --------------
__global__ void k_prep(const float* __restrict__ img, unsigned short* __restrict__ IMG2,
                       float2* __restrict__ W,
                       float2* __restrict__ U2, float2* __restrict__ Hb,
                       const float* __restrict__ meanp,
                       double xstart, double xstep, double xstop,
                       double fstart, double fstep, double fstop,
                       float ap_f) {
#pragma clang fp contract(off)
    int idx = blockIdx.x * 256 + threadIdx.x;
    if (idx < 3 * NP) {
        int c = idx / NP, ij = idx % NP, i = ij / M, j = ij % M;
        const float wls[3] = {6.1e-07f, 5.3e-07f, 4.7e-07f};
        float wl = wls[c];
        float ki = ((float)6.283185307179586) / wl;
        float d  = meanp[0];
        float d2 = d * d;

        float x  = (i == 254) ? (float)xstop : (float)((double)i * xstep + xstart);
        float y  = (j == 254) ? (float)xstop : (float)((double)j * xstep + xstart);
        float fx = (i == 254) ? (float)fstop : (float)((double)i * fstep + fstart);
        float fy = (j == 254) ? (float)fstop : (float)((double)j * fstep + fstart);

        float xx = x * x, yy = y * y;
        float X1Y1 = xx + yy;

        float s  = sqrtf(X1Y1 + d2);
        float th = ki * s;
        float A  = (sqrtf(X1Y1) / ap_f <= 1.0f) ? 1.0f : 0.0f;
        float2 u2v;
        if (A != 0.0f) u2v = make_float2((float)cos((double)th), (float)sin((double)th));
        else           u2v = make_float2(0.0f, 0.0f);

        float a = wl * fx, b = wl * fy;
        float arg = (1.0f - a * a) - b * b;
        float FXY = sqrtf(fmaxf(arg, 0.0f));
        float Hv  = (sqrtf(fx * fx + fy * fy) < (1.0f / wl)) ? 1.0f : 0.0f;
        float kd  = ki * d;
        float ph  = kd * FXY;
        float cph = (float)cos((double)ph), sph = (float)sin((double)ph);
        float2 hv = make_float2(Hv * cph, Hv * sph);

        U2[idx] = u2v;
        Hb[idx] = hv;
        return;
    }
    if (idx < 4 * NP) {
        int e = idx - 3 * NP;
        int n = e / M, k = e % M;
        int m = (n * k) % M;
        double ang = -2.0 * 3.14159265358979323846 * (double)m / 255.0;
        W[e] = make_float2((float)cos(ang), (float)sin(ang));
        return;
    }
    int e = idx - 4 * NP;
    if (e >= IMG_SIDE) return;
    int ch = e / IMG_CH, rem = e % IMG_CH;
    int prow = rem / IMG_COLS, pcol = rem % IMG_COLS;
    int a = prow - 80, b = pcol - 80;
    float v = 0.0f;
    if (a >= 0 && a < M && b >= 0 && b < M) v = img[(a * M + b) * 3 + ch];
    unsigned short hi = f2bf(v);
    unsigned short lo = f2bf(v - bf2f(hi));
    IMG2[e] = hi;
    IMG2[IMG_SIDE + e] = lo;
}

// ---------------- batched f32 complex GEMM, 16x32 tile, BK=32 ---------------
// R22: K-step 32 -> 8 kt iterations, 16 barriers/block (was 32). Per-output
// k accumulation remains sequential 0..255 -> bit-identical to R20.
// 256 threads; per kt each thread stages 2 A + 4 B float2 scalars,
// prefetched one kt ahead.
#define CG_LOAD(KT, VA0, VA1, WB0, WB1, WB2, WB3) { \
    int k0_ = (KT) * 32; \
    { int idx_ = threadIdx.x; \
      int r_ = idx_ >> 5, c_ = idx_ & 31; \
      int gi_ = i0 + r_, gk_ = k0_ + c_; \
      VA0 = (gi_ < M && gk_ < M) ? Ab[gi_ * M + gk_] : make_float2(0.f, 0.f); \
      if (conjA) VA0.y = -VA0.y; } \
    { int idx_ = threadIdx.x + 256; \
      int r_ = idx_ >> 5, c_ = idx_ & 31; \
      int gi_ = i0 + r_, gk_ = k0_ + c_; \
      VA1 = (gi_ < M && gk_ < M) ? Ab[gi_ * M + gk_] : make_float2(0.f, 0.f); \
      if (conjA) VA1.y = -VA1.y; } \
    { int idx_ = threadIdx.x; \
      int r2_ = idx_ >> 5, c2_ = idx_ & 31; \
      int gk2_ = k0_ + r2_, gj_ = j0 + c2_; \
      WB0 = make_float2(0.f, 0.f); \
      if (gk2_ < M && gj_ < M) { \
          WB0 = Bb[gk2_ * M + gj_]; \
          if (B2b) { float2 z_ = B2b[gk2_ * M + gj_]; \
              WB0 = make_float2(WB0.x * z_.x - WB0.y * z_.y, WB0.x * z_.y + WB0.y * z_.x); } \
      } \
      if (conjB) WB0.y = -WB0.y; } \
    { int idx_ = threadIdx.x + 256; \
      int r2_ = idx_ >> 5, c2_ = idx_ & 31; \
      int gk2_ = k0_ + r2_, gj_ = j0 + c2_; \
      WB1 = make_float2(0.f, 0.f); \
      if (gk2_ < M && gj_ < M) { \
          WB1 = Bb[gk2_ * M + gj_]; \
          if (B2b) { float2 z_ = B2b[gk2_ * M + gj_]; \
              WB1 = make_float2(WB1.x * z_.x - WB1.y * z_.y, WB1.x * z_.y + WB1.y * z_.x); } \
      } \
      if (conjB) WB1.y = -WB1.y; } \
    { int idx_ = threadIdx.x + 512; \
      int r2_ = idx_ >> 5, c2_ = idx_ & 31; \
      int gk2_ = k0_ + r2_, gj_ = j0 + c2_; \
      WB2 = make_float2(0.f, 0.f); \
      if (gk2_ < M && gj_ < M) { \
          WB2 = Bb[gk2_ * M + gj_]; \
          if (B2b) { float2 z_ = B2b[gk2_ * M + gj_]; \
              WB2 = make_float2(WB2.x * z_.x - WB2.y * z_.y, WB2.x * z_.y + WB2.y * z_.x); } \
      } \
      if (conjB) WB2.y = -WB2.y; } \
    { int idx_ = threadIdx.x + 768; \
      int r2_ = idx_ >> 5, c2_ = idx_ & 31; \
      int gk2_ = k0_ + r2_, gj_ = j0 + c2_; \
      WB3 = make_float2(0.f, 0.f); \
      if (gk2_ < M && gj_ < M) { \
          WB3 = Bb[gk2_ * M + gj_]; \
          if (B2b) { float2 z_ = B2b[gk2_ * M + gj_]; \
              WB3 = make_float2(WB3.x * z_.x - WB3.y * z_.y, WB3.x * z_.y + WB3.y * z_.x); } \
      } \
      if (conjB) WB3.y = -WB3.y; } }

__global__ __launch_bounds__(256)
void k_cgemm(const float2* __restrict__ A, int aBatch,
             const float2* __restrict__ B, const float2* __restrict__ B2,
             int bBatch, float2* __restrict__ C,
             int conjA, int conjB, float scale) {
    __shared__ float2 As[16][33];
    __shared__ float2 Bs[32][33];
    int c = blockIdx.z;
    int tx = threadIdx.x & 15, ty = threadIdx.x >> 4;
    int i0 = blockIdx.y * 16, j0 = blockIdx.x * 32;
    const float2* Ab = A + (size_t)c * aBatch;
    const float2* Bb = B + (size_t)c * bBatch;
    const float2* B2b = B2 ? (B2 + (size_t)c * bBatch) : nullptr;
    float2 a00 = {0,0}, a01 = {0,0};

    int wrA0 = threadIdx.x >> 5,          wcA0 = threadIdx.x & 31;
    int wrA1 = (threadIdx.x + 256) >> 5,  wcA1 = (threadIdx.x + 256) & 31;
    int wrB0 = threadIdx.x >> 5,          wcB0 = threadIdx.x & 31;
    int wrB1 = (threadIdx.x + 256) >> 5,  wcB1 = (threadIdx.x + 256) & 31;
    int wrB2 = (threadIdx.x + 512) >> 5,  wcB2 = (threadIdx.x + 512) & 31;
    int wrB3 = (threadIdx.x + 768) >> 5,  wcB3 = (threadIdx.x + 768) & 31;

    float2 vA0, vA1, wB0, wB1, wB2, wB3;    // current kt staging values
    float2 nA0, nA1, nB0, nB1, nB2, nB3;    // next kt
    CG_LOAD(0, vA0, vA1, wB0, wB1, wB2, wB3)

    for (int kt = 0; kt < 8; ++kt) {
        As[wrA0][wcA0] = vA0;  As[wrA1][wcA1] = vA1;
        Bs[wrB0][wcB0] = wB0;  Bs[wrB1][wcB1] = wB1;
        Bs[wrB2][wcB2] = wB2;  Bs[wrB3][wcB3] = wB3;
        if (kt < 7) { CG_LOAD(kt + 1, nA0, nA1, nB0, nB1, nB2, nB3) }
        __syncthreads();
#pragma unroll
        for (int kk = 0; kk < 32; ++kk) {
            float2 p = As[ty][kk];
            float2 u = Bs[kk][tx], v = Bs[kk][tx + 16];
            a00.x += p.x * u.x - p.y * u.y;  a00.y += p.x * u.y + p.y * u.x;
            a01.x += p.x * v.x - p.y * v.y;  a01.y += p.x * v.y + p.y * v.x;
        }
        __syncthreads();
        vA0 = nA0; vA1 = nA1; wB0 = nB0; wB1 = nB1; wB2 = nB2; wB3 = nB3;
    }
    float2* Cb = C + (size_t)c * NP;
    int gi  = i0 + ty;
    int gj0 = j0 + tx, gj1 = j0 + tx + 16;
    if (gi < M && gj0 < M) Cb[gi * M + gj0] = make_float2(a00.x * scale, a00.y * scale);
    if (gi < M && gj1 < M) Cb[gi * M + gj1] = make_float2(a01.x * scale, a01.y * scale);
}

// ---------------- S = sum u3^2 (f64 accumulate over f32 u3) ----------------
__global__ void k_sred(const float2* __restrict__ U3, double2* __restrict__ spart) {
    __shared__ double sx[256], sy[256];
    int t = threadIdx.x;
    double ax = 0.0, ay = 0.0;
    for (int i = blockIdx.x * 256 + t; i < 3 * NP; i += 64 * 256) {
        double zx = (double)U3[i].x, zy = (double)U3[i].y;
        ax += zx * zx - zy * zy;
        ay += 2.0 * zx * zy;
    }
    sx[t] = ax; sy[t] = ay;
    __syncthreads();
    for (int w = 128; w > 0; w >>= 1) {
        if (t < w) { sx[t] += sx[t + w]; sy[t] += sy[t + w]; }
        __syncthreads();
    }
    if (t == 0) spart[blockIdx.x] = make_double2(sx[0], sy[0]);
}

// ---------------- final S scalars (once, not per-thread in k_p4) ------------
__global__ void k_sfin(const double2* __restrict__ spart, double* __restrict__ sfin) {
    if (threadIdx.x != 0 || blockIdx.x != 0) return;
    double rx = 0.0, ry = 0.0;
    for (int i = 0; i < 64; ++i) { rx += spart[i].x; ry += spart[i].y; }
    double dsx = rx + 1e-7, dsy = ry;            // same association as before
    sfin[0] = dsx;
    sfin[1] = dsy;
    sfin[2] = 1.0 / (dsx * dsx + dsy * dsy);
}

// ---------------- psf -> P4 sliding-window bf16 hi/lo table -----------------
// P4[ch][di][u][t] = psf[di][u-16+t]  (u 0..303, t 0..7, zero-padded)
__global__ void k_p4(const float2* __restrict__ U3, const double* __restrict__ sfin,
                     unsigned short* __restrict__ P4) {
    int idx = blockIdx.x * 256 + threadIdx.x;
    if (idx >= P4_SIDE) return;
    double dsx = sfin[0], dsy = sfin[1], inv = sfin[2];
    int ch = idx / P4_CH, rem = idx % P4_CH;
    int di = rem / P4_DI, rem2 = rem % P4_DI;
    int u = rem2 / 8, t = rem2 % 8;
    int p = u - 16 + t;
    float v = 0.0f;
    if (di < M && p >= 0 && p < M) {
        float2 zf = U3[(ch * M + di) * M + p];
        double zx = (double)zf.x, zy = (double)zf.y;
        double zr = zx * zx - zy * zy;
        double zi = 2.0 * zx * zy;
        v = (float)((zr * dsx + zi * dsy) * inv);
    }
    unsigned short hi = f2bf(v);
    unsigned short lo = f2bf(v - bf2f(hi));
    P4[idx] = hi;
    P4[P4_SIDE + idx] = lo;
}

// ---------------- MFMA conv: banded-Toeplitz implicit GEMM ------------------
// R18/R20-exact: 4 waves, TWO 16x16 output tiles (j0, j0+16), one (ch,
// 16-di chunk); one-dloc-ahead A prefetch with sched_barrier fences;
// launch_bounds(256,2) (R19: needs the 256-VGPR budget; (256,4) spills).
// R21 lesson: LDS bank conflicts here are HIDDEN — do not swizzle (the
// XOR address math costs more than the conflicts).
// A[m=lane&15][k=8q+t] = psf[di][32c + 8q + t - m]   (window u = su0+32c)
// B[k=8q+t][n=lane&15] = img[i0+n+di-80][jT-80+32c+8q+t],  jT = j0 | j0+16
// D: row(=m/j) = 4q+reg, col(=n/i) = lane&15.
constexpr int LDS_STRIDE = 312;    // shorts; 624 B rows, 16B aligned

#define SB __builtin_amdgcn_sched_barrier(0);

#define REP9(OP) OP(0) OP(1) OP(2) OP(3) OP(4) OP(5) OP(6) OP(7) OP(8)

#define DECLA(i) short8 Ah_##i, Al_##i;
#define DECLB(i) short8 Bh_##i, Bl_##i;

#define LDA(i) Ah_##i = *(const short8*)(prH + 256 * i); \
               Al_##i = *(const short8*)(prL + 256 * i);
#define LDB(i) Bh_##i = *(const short8*)(prH + 256 * i); \
               Bl_##i = *(const short8*)(prL + 256 * i);
#define LOADA(dl) { const unsigned short* prH = pHc + (size_t)(d0 + (dl)) * P4_DI + aoff; \
                    const unsigned short* prL = pLc + (size_t)(d0 + (dl)) * P4_DI + aoff; \
                    REP9(LDA) }
#define LOADB(dl) { const unsigned short* prH = pHc + (size_t)(d0 + (dl)) * P4_DI + aoff; \
                    const unsigned short* prL = pLc + (size_t)(d0 + (dl)) * P4_DI + aoff; \
                    REP9(LDB) }

#define CMA(i) { \
    short8 bh0 = *(const short8*)&ldsI[0][rrow][32 * i + 8 * q]; \
    short8 bl0 = *(const short8*)&ldsI[1][rrow][32 * i + 8 * q]; \
    short8 bh1 = *(const short8*)&ldsI[0][rrow][32 * i + 8 * q + 16]; \
    short8 bl1 = *(const short8*)&ldsI[1][rrow][32 * i + 8 * q + 16]; \
    aHH0 = __builtin_amdgcn_mfma_f32_16x16x32_bf16(Ah_##i, bh0, aHH0, 0, 0, 0); \
    aHL0 = __builtin_amdgcn_mfma_f32_16x16x32_bf16(Ah_##i, bl0, aHL0, 0, 0, 0); \
    aLH0 = __builtin_amdgcn_mfma_f32_16x16x32_bf16(Al_##i, bh0, aLH0, 0, 0, 0); \
    aHH1 = __builtin_amdgcn_mfma_f32_16x16x32_bf16(Ah_##i, bh1, aHH1, 0, 0, 0); \
    aHL1 = __builtin_amdgcn_mfma_f32_16x16x32_bf16(Ah_##i, bl1, aHL1, 0, 0, 0); \
    aLH1 = __builtin_amdgcn_mfma_f32_16x16x32_bf16(Al_##i, bh1, aLH1, 0, 0, 0); }
#define CMB(i) { \
    short8 bh0 = *(const short8*)&ldsI[0][rrow][32 * i + 8 * q]; \
    short8 bl0 = *(const short8*)&ldsI[1][rrow][32 * i + 8 * q]; \
    short8 bh1 = *(const short8*)&ldsI[0][rrow][32 * i + 8 * q + 16]; \
    short8 bl1 = *(const short8*)&ldsI[1][rrow][32 * i + 8 * q + 16]; \
    aHH0 = __builtin_amdgcn_mfma_f32_16x16x32_bf16(Bh_##i, bh0, aHH0, 0, 0, 0); \
    aHL0 = __builtin_amdgcn_mfma_f32_16x16x32_bf16(Bh_##i, bl0, aHL0, 0, 0, 0); \
    aLH0 = __builtin_amdgcn_mfma_f32_16x16x32_bf16(Bl_##i, bh0, aLH0, 0, 0, 0); \
    aHH1 = __builtin_amdgcn_mfma_f32_16x16x32_bf16(Bh_##i, bh1, aHH1, 0, 0, 0); \
    aHL1 = __builtin_amdgcn_mfma_f32_16x16x32_bf16(Bh_##i, bl1, aHL1, 0, 0, 0); \
    aLH1 = __builtin_amdgcn_mfma_f32_16x16x32_bf16(Bl_##i, bh1, aLH1, 0, 0, 0); }
#define COMPA(dl) { int rrow = ln + (dl); REP9(CMA) }
#define COMPB(dl) { int rrow = ln + (dl); REP9(CMB) }

__global__ __launch_bounds__(256, 2)
void k_conv(const unsigned short* __restrict__ IMG2,
            const unsigned short* __restrict__ P4,
            float* __restrict__ PART) {
    __shared__ __align__(16) unsigned short ldsI[2][31][LDS_STRIDE];

    int tid  = threadIdx.x;
    int w    = tid >> 6;           // wave 0..3
    int lane = tid & 63;
    int ln   = lane & 15;          // m for A, n for B/C-col
    int q    = lane >> 4;          // 0..3
    int j0 = blockIdx.x * 32;      // TWO 16-col tiles: j0 and j0+16
    int i0 = blockIdx.y * 16;
    int bz = blockIdx.z;           // ch*16 + chunk
    int ch = bz >> 4, chunk = bz & 15;
    int d0 = chunk << 4;

    const unsigned short* imgH = IMG2 + ch * IMG_CH;
    const unsigned short* imgL = imgH + IMG_SIDE;
    const unsigned short* pHc  = P4 + ch * P4_CH;
    const unsigned short* pLc  = pHc + P4_SIDE;

    // sliding-window index: u = su0 + 32*cc, su0 = 16 + 8q - ln in 1..40
    int su0  = 16 + 8 * q - ln;
    int aoff = su0 * 8;                    // shorts; + 256 per cc step

    f32x4 aHH0 = {0.f,0.f,0.f,0.f}, aHL0 = {0.f,0.f,0.f,0.f}, aLH0 = {0.f,0.f,0.f,0.f};
    f32x4 aHH1 = {0.f,0.f,0.f,0.f}, aHL1 = {0.f,0.f,0.f,0.f}, aLH1 = {0.f,0.f,0.f,0.f};

    REP9(DECLA)
    REP9(DECLB)

    int dbase = 4 * w;
    LOADA(dbase + 0)               // in flight during staging

    // ---- stage image tile: rows i0+d0 .. +30, cols j0 .. j0+303, hi+lo ----
    int row0 = i0 + d0;
    for (int idx = tid; idx < 2 * 31 * 38; idx += 256) {
        int plane = idx / (31 * 38);
        int rem = idx - plane * (31 * 38);
        int r = rem / 38, c = rem - r * 38;
        const unsigned short* src =
            (plane ? imgL : imgH) + (size_t)(row0 + r) * IMG_COLS + j0 + c * 8;
        *(short8*)&ldsI[plane][r][c * 8] = *(const short8*)src;
    }
    __syncthreads();

    LOADB(dbase + 1)
    SB
    COMPA(dbase + 0)
    SB
    LOADA(dbase + 2)
    SB
    COMPB(dbase + 1)
    SB
    LOADB(dbase + 3)
    SB
    COMPA(dbase + 2)
    SB
    COMPB(dbase + 3)

    // ---- combine the three precision terms, then reduce across the 4 waves
    f32x4 tot0, tot1;
#pragma unroll
    for (int r = 0; r < 4; ++r) {
        tot0[r] = aHH0[r] + aHL0[r] + aLH0[r];
        tot1[r] = aHH1[r] + aHL1[r] + aLH1[r];
    }

    __syncthreads();                       // everyone done reading image LDS
    float* red = (float*)&ldsI[0][0][0];
    if (w) {
#pragma unroll
        for (int r = 0; r < 4; ++r) {
            red[((w - 1) * 64 + lane) * 8 + r]     = tot0[r];
            red[((w - 1) * 64 + lane) * 8 + 4 + r] = tot1[r];
        }
    }
    __syncthreads();
    if (w == 0) {
#pragma unroll
        for (int wv = 0; wv < 3; ++wv)
#pragma unroll
            for (int r = 0; r < 4; ++r) {
                tot0[r] += red[(wv * 64 + lane) * 8 + r];
                tot1[r] += red[(wv * 64 + lane) * 8 + 4 + r];
            }
        // D row = 4q+reg -> j = jT+4q+reg ; D col = ln -> i = i0+ln
        float* op = PART + (size_t)bz * (RESO * RESO) + (i0 + ln) * RESO + j0 + 4 * q;
        float4 o0; o0.x = tot0[0]; o0.y = tot0[1]; o0.z = tot0[2]; o0.w = tot0[3];
        float4 o1; o1.x = tot1[0]; o1.y = tot1[1]; o1.z = tot1[2]; o1.w = tot1[3];
        *(float4*)op = o0;
        *(float4*)(op + 16) = o1;
    }
}

// ---------------- reduce partials + clip + layout (i,j,c) ----------------
__global__ void k_out(const float* __restrict__ PART, float* __restrict__ out) {
    int idx = blockIdx.x * 256 + threadIdx.x;
    if (idx >= 3 * RESO * RESO) return;
    int c = idx / (RESO * RESO), ij = idx % (RESO * RESO);
    float s = 0.0f;
    for (int kz = 0; kz < 16; ++kz)
        s += PART[(size_t)(c * 16 + kz) * (RESO * RESO) + ij];
    s = fminf(fmaxf(s, 0.0f), 1.0f);
    int i = ij / RESO, j = ij % RESO;
    out[(i * RESO + j) * 3 + c] = s;
}

// ---------------------------------------------------------------------------
extern "C" void kernel_launch(void* const* d_in, const int* in_sizes, int n_in,
                              void* d_out, int out_size, void* d_ws, size_t ws_size,
                              hipStream_t stream) {
    const float* image = (const float*)d_in[0];   // (255,255,3)
    const float* depth = (const float*)d_in[1];   // (255,255)
    float* out = (float*)d_out;                   // (160,160,3)

    // workspace carve (256B aligned), ~28 MB
    char* p = (char*)d_ws;
    auto alloc = [&](size_t bytes) { void* r = (void*)p; p += (bytes + 255) & ~(size_t)255; return r; };
    float*   meanp = (float*)alloc(4);
    float*   mval  = (float*)alloc(MAXN * 4);
    double*  sfin  = (double*)alloc(3 * 8);
    float2*  Wf    = (float2*)alloc((size_t)NP * 8);
    float2*  UH    = (float2*)alloc((size_t)6 * NP * 8);   // U2 | Hb
    float2*  Td    = (float2*)alloc((size_t)6 * NP * 8);
    float2*  EF    = (float2*)alloc((size_t)6 * NP * 8);   // FU | FH
    float2*  U3    = (float2*)alloc((size_t)3 * NP * 8);
    double2* spart = (double2*)alloc(64 * 16);
    unsigned short* P4   = (unsigned short*)alloc((size_t)2 * P4_SIDE * 2);
    unsigned short* IMG2 = (unsigned short*)alloc((size_t)2 * IMG_SIDE * 2);
    float*   PART  = (float*)alloc((size_t)48 * RESO * RESO * 4);

    float2* U2 = UH;
    float2* Hb = UH + (size_t)3 * NP;

    // exact python-f64 scalar path
    double dx = 0.002 / 255.0;
    double Lx = dx * 255.0;
    double ap = (Lx / 2.0) * 0.1 + 1e-7;
    float ap_f = (float)ap;

    double xstart = -(Lx / 2.0);
    double xstop  =  Lx / 2.0;
    double xstep  = (xstop - xstart) / 254.0;
    double fstart = -1.0 / (2.0 * dx);
    double fstop  =  1.0 / (2.0 * dx);
    double fstep  = (fstop - fstart) / 254.0;

    k_mleaf<<<(PW.nNode + 255) / 256, 256, 0, stream>>>(depth, mval);
    k_mtree<<<1, 256, 0, stream>>>(depth, mval, meanp);
    int gprep = (4 * NP + IMG_SIDE + 255) / 256;   // 3201
    k_prep<<<gprep, 256, 0, stream>>>(image, IMG2, Wf, U2, Hb, meanp,
                                      xstart, xstep, xstop,
                                      fstart, fstep, fstop, ap_f);

    dim3 bb(256);
    k_cgemm<<<dim3(8, 16, 6), bb, 0, stream>>>(Wf, 0, UH, nullptr, NP, Td, 0, 0, 1.0f);
    k_cgemm<<<dim3(8, 16, 6), bb, 0, stream>>>(Td, NP, Wf, nullptr, 0, EF, 0, 0, 1.0f);
    k_cgemm<<<dim3(8, 16, 3), bb, 0, stream>>>(Wf, 0, EF + (size_t)3 * NP, EF, NP,
                                               Td, 1, 0, 1.0f / 255.0f);
    k_cgemm<<<dim3(8, 16, 3), bb, 0, stream>>>(Td, NP, Wf, nullptr, 0, U3, 0, 1,
                                               1.0f / 255.0f);

    k_sred<<<64, 256, 0, stream>>>(U3, spart);
    k_sfin<<<1, 64, 0, stream>>>(spart, sfin);
    k_p4<<<(P4_SIDE + 255) / 256, 256, 0, stream>>>(U3, sfin, P4);

    k_conv<<<dim3(5, 10, 48), 256, 0, stream>>>(IMG2, P4, PART);
    k_out<<<300, 256, 0, stream>>>(PART, out);
}

// Round 13
// 254.609 us; speedup vs baseline: 1.2118x; 1.2118x over previous
//
#include <hip/hip_runtime.h>
#include <hip/hip_bf16.h>
#include <math.h>

// ---------------------------------------------------------------------------
// MjCambrianOptics. Correctness-critical (R7-validated, DO NOT TOUCH):
//   * mean(depth) = numpy BUFFERED reduce: seed a[0], then sequential
//     += pairwise_sum(8192-chunk), 128-leaf/8-acc recursion.
//   * ki = fl32(2pi)/fl32(wl) f32 divide; linspace f64-cast; th/ph op order.
// R11: conv -> MFMA (banded-Toeplitz implicit GEMM, split-bf16 hi/lo).
// R15: sched_barrier-pinned one-dloc-ahead A prefetch.
// R17: sliding-window P4 => coalesced A-loads. 162->82 us (CONFIRMED).
// R18: two j-tiles/block (A reuse). 82->55.6.
// R19: FAILED (256,4) VGPR cap -> spill. 2 blocks/CU is a HARD constraint.
// R20: (256,2) + 16x32 cgemm 128-blocks/plane. tot 252.7 (best).
// R21: both halves regressed (swizzle: conflicts were hidden; 128-thr 2x2:
//      halved latency-hiding waves). Reverted.
// R22: BK=32 cgemm regressed (+56 us): 6-deep guarded prefetch chain delayed
//      every LDS-store phase -> cgemm is NOT barrier-bound. Reverted.
// R24: R20-exact + W-table: W[n,k]=cis(-2pi((n*k)%255)/255) has only 255
//      distinct entries; compute them once (identical f64 expression) and
//      look up in k_prep. Bit-identical; removes 65k f64 sincos.
// ---------------------------------------------------------------------------

constexpr int M   = 255;
constexpr int NP  = M * M;        // 65025
constexpr int RESO = 160;

// IMG2 (padded bf16 image, hi|lo): [side][ch][row 0..415][col 0..447]
constexpr int IMG_ROWS = 416, IMG_COLS = 448;
constexpr int IMG_CH   = IMG_ROWS * IMG_COLS;      // 186368
constexpr int IMG_SIDE = 3 * IMG_CH;               // 559104
// P4 sliding-window table (bf16 hi|lo): [side][ch][di 0..255][u 0..303][t 0..7]
// entry (di,u,t) = psf[di][u-16+t], zero-padded outside [0,M)
constexpr int P4_DI   = 304 * 8;                   // 2432 shorts per di
constexpr int P4_CH   = 256 * P4_DI;               // 622592
constexpr int P4_SIDE = 3 * P4_CH;                 // 1867776

typedef __attribute__((ext_vector_type(8))) short short8;
typedef __attribute__((ext_vector_type(4))) float f32x4;

__device__ __forceinline__ unsigned short f2bf(float f) {
    unsigned int u = __float_as_uint(f);
    unsigned int r = (u + 0x7fffu + ((u >> 16) & 1u)) >> 16;
    return (unsigned short)r;
}
__device__ __forceinline__ float bf2f(unsigned short h) {
    return __uint_as_float(((unsigned int)h) << 16);
}

// ---------------- numpy buffered-reduce pairwise forest (compile-time) ------
constexpr int MAXN = 1100;
struct PWForest {
    int kind[MAXN];
    int off[MAXN], len[MAXN];
    int li[MAXN], ri[MAXN];
    int lvl[MAXN];
    int nNode, nLeaf, maxLvl;
    int roots[16], nRoots;
};
constexpr int pwf_build(PWForest& T, int o, int n) {
    if (n <= 128) {
        int id = T.nNode++;
        T.kind[id] = 0; T.off[id] = o; T.len[id] = n;
        T.lvl[id] = 0; T.nLeaf++;
        return id;
    }
    int n2 = (n / 2) - ((n / 2) % 8);
    int a = pwf_build(T, o, n2);
    int b = pwf_build(T, o + n2, n - n2);
    int id = T.nNode++;
    T.kind[id] = 1; T.li[id] = a; T.ri[id] = b;
    int l = (T.lvl[a] > T.lvl[b] ? T.lvl[a] : T.lvl[b]) + 1;
    T.lvl[id] = l; if (l > T.maxLvl) T.maxLvl = l;
    return id;
}
constexpr PWForest pwf_make() {
    PWForest T{};
    int pos = 1, rem = NP - 1;            // reduce seeds with a[0]
    while (rem > 0) {
        int c = rem > 8192 ? 8192 : rem;  // nditer buffer = 8192 elements
        T.roots[T.nRoots++] = pwf_build(T, pos, c);
        pos += c; rem -= c;
    }
    return T;
}
constexpr PWForest PW = pwf_make();
static_assert(PW.nNode <= MAXN, "forest overflow");
static_assert(PW.nRoots == 8, "chunk count");

// leaves are independent: one THREAD per node id, exact per-leaf arithmetic
__global__ void k_mleaf(const float* __restrict__ depth, float* __restrict__ val) {
    int id = blockIdx.x * 256 + threadIdx.x;
    if (id >= PW.nNode || PW.kind[id] != 0) return;
    const float* a = depth + PW.off[id];
    int n = PW.len[id];
    float r0 = a[0], r1 = a[1], r2 = a[2], r3 = a[3];
    float r4 = a[4], r5 = a[5], r6 = a[6], r7 = a[7];
    int lim = n - (n % 8);
    int i = 8;
    for (; i < lim; i += 8) {
        r0 += a[i + 0]; r1 += a[i + 1]; r2 += a[i + 2]; r3 += a[i + 3];
        r4 += a[i + 4]; r5 += a[i + 5]; r6 += a[i + 6]; r7 += a[i + 7];
    }
    float res = ((r0 + r1) + (r2 + r3)) + ((r4 + r5) + (r6 + r7));
    for (; i < n; ++i) res += a[i];
    val[id] = res;
}

// internal levels + root chain, single block (exact same order as before)
__global__ void k_mtree(const float* __restrict__ depth, float* __restrict__ val,
                        float* __restrict__ meanp) {
    int tid = threadIdx.x;
    for (int l = 1; l <= PW.maxLvl; ++l) {
        for (int id = tid; id < PW.nNode; id += 256)
            if (PW.kind[id] == 1 && PW.lvl[id] == l)
                val[id] = val[PW.li[id]] + val[PW.ri[id]];
        __syncthreads();
    }
    if (tid == 0) {
        float io1 = depth[0];
        for (int r = 0; r < PW.nRoots; ++r)
            io1 = io1 + val[PW.roots[r]];
        meanp[0] = io1 / 65025.0f;
    }
}

// ---------------- 255-entry W root table (bit-identical expression) --------
__global__ void k_wtab(float2* __restrict__ wtab) {
    int m = threadIdx.x;
    if (m >= M) return;
    double ang = -2.0 * 3.14159265358979323846 * (double)m / 255.0;
    wtab[m] = make_float2((float)cos(ang), (float)sin(ang));
}

// ---------------- prep: u2H fields + DFT W + padded bf16 image --------------
__global__ void k_prep(const float* __restrict__ img, unsigned short* __restrict__ IMG2,
                       float2* __restrict__ W, const float2* __restrict__ wtab,
                       float2* __restrict__ U2, float2* __restrict__ Hb,
                       const float* __restrict__ meanp,
                       double xstart, double xstep, double xstop,
                       double fstart, double fstep, double fstop,
                       float ap_f) {
#pragma clang fp contract(off)
    int idx = blockIdx.x * 256 + threadIdx.x;
    if (idx < 3 * NP) {
        int c = idx / NP, ij = idx % NP, i = ij / M, j = ij % M;
        const float wls[3] = {6.1e-07f, 5.3e-07f, 4.7e-07f};
        float wl = wls[c];
        float ki = ((float)6.283185307179586) / wl;
        float d  = meanp[0];
        float d2 = d * d;

        float x  = (i == 254) ? (float)xstop : (float)((double)i * xstep + xstart);
        float y  = (j == 254) ? (float)xstop : (float)((double)j * xstep + xstart);
        float fx = (i == 254) ? (float)fstop : (float)((double)i * fstep + fstart);
        float fy = (j == 254) ? (float)fstop : (float)((double)j * fstep + fstart);

        float xx = x * x, yy = y * y;
        float X1Y1 = xx + yy;

        float s  = sqrtf(X1Y1 + d2);
        float th = ki * s;
        float A  = (sqrtf(X1Y1) / ap_f <= 1.0f) ? 1.0f : 0.0f;
        float2 u2v;
        if (A != 0.0f) u2v = make_float2((float)cos((double)th), (float)sin((double)th));
        else           u2v = make_float2(0.0f, 0.0f);

        float a = wl * fx, b = wl * fy;
        float arg = (1.0f - a * a) - b * b;
        float FXY = sqrtf(fmaxf(arg, 0.0f));
        float Hv  = (sqrtf(fx * fx + fy * fy) < (1.0f / wl)) ? 1.0f : 0.0f;
        float kd  = ki * d;
        float ph  = kd * FXY;
        float cph = (float)cos((double)ph), sph = (float)sin((double)ph);
        float2 hv = make_float2(Hv * cph, Hv * sph);

        U2[idx] = u2v;
        Hb[idx] = hv;
        return;
    }
    if (idx < 4 * NP) {
        int e = idx - 3 * NP;
        int n = e / M, k = e % M;
        int m = (n * k) % M;
        W[e] = wtab[m];                    // bit-identical: same f64 expr in k_wtab
        return;
    }
    int e = idx - 4 * NP;
    if (e >= IMG_SIDE) return;
    int ch = e / IMG_CH, rem = e % IMG_CH;
    int prow = rem / IMG_COLS, pcol = rem % IMG_COLS;
    int a = prow - 80, b = pcol - 80;
    float v = 0.0f;
    if (a >= 0 && a < M && b >= 0 && b < M) v = img[(a * M + b) * 3 + ch];
    unsigned short hi = f2bf(v);
    unsigned short lo = f2bf(v - bf2f(hi));
    IMG2[e] = hi;
    IMG2[IMG_SIDE + e] = lo;
}

// ---------------- batched f32 complex GEMM, 16x32 tile, 2/thread ------------
// R20-exact: 128 blocks/plane. Per-output K accumulation sequence unchanged
// (same kt/kk order, same FMA expressions) -> bit-identical.
// One-kt-ahead register prefetch (1 A + 2 B float2 scalars).
#define CG_LOAD(KT, VA, WB0, WB1) { \
    int k0_ = (KT) * 16; \
    { int r_ = threadIdx.x >> 4, c_ = threadIdx.x & 15; \
      int gi_ = i0 + r_, gk_ = k0_ + c_; \
      VA = (gi_ < M && gk_ < M) ? Ab[gi_ * M + gk_] : make_float2(0.f, 0.f); \
      if (conjA) VA.y = -VA.y; } \
    { int r2_ = threadIdx.x >> 5, c2_ = threadIdx.x & 31; \
      int gk2_ = k0_ + r2_, gj_ = j0 + c2_; \
      WB0 = make_float2(0.f, 0.f); \
      if (gk2_ < M && gj_ < M) { \
          WB0 = Bb[gk2_ * M + gj_]; \
          if (B2b) { float2 z_ = B2b[gk2_ * M + gj_]; \
              WB0 = make_float2(WB0.x * z_.x - WB0.y * z_.y, WB0.x * z_.y + WB0.y * z_.x); } \
      } \
      if (conjB) WB0.y = -WB0.y; } \
    { int idx_ = threadIdx.x + 256; \
      int r2_ = idx_ >> 5, c2_ = idx_ & 31; \
      int gk2_ = k0_ + r2_, gj_ = j0 + c2_; \
      WB1 = make_float2(0.f, 0.f); \
      if (gk2_ < M && gj_ < M) { \
          WB1 = Bb[gk2_ * M + gj_]; \
          if (B2b) { float2 z_ = B2b[gk2_ * M + gj_]; \
              WB1 = make_float2(WB1.x * z_.x - WB1.y * z_.y, WB1.x * z_.y + WB1.y * z_.x); } \
      } \
      if (conjB) WB1.y = -WB1.y; } }

__global__ __launch_bounds__(256)
void k_cgemm(const float2* __restrict__ A, int aBatch,
             const float2* __restrict__ B, const float2* __restrict__ B2,
             int bBatch, float2* __restrict__ C,
             int conjA, int conjB, float scale) {
    __shared__ float2 As[16][17];
    __shared__ float2 Bs[16][33];
    int c = blockIdx.z;
    int tx = threadIdx.x & 15, ty = threadIdx.x >> 4;
    int i0 = blockIdx.y * 16, j0 = blockIdx.x * 32;
    const float2* Ab = A + (size_t)c * aBatch;
    const float2* Bb = B + (size_t)c * bBatch;
    const float2* B2b = B2 ? (B2 + (size_t)c * bBatch) : nullptr;
    float2 a00 = {0,0}, a01 = {0,0};

    int wrA  = threadIdx.x >> 4,  wcA  = threadIdx.x & 15;
    int wrB0 = threadIdx.x >> 5,  wcB0 = threadIdx.x & 31;
    int wrB1 = (threadIdx.x + 256) >> 5, wcB1 = (threadIdx.x + 256) & 31;

    float2 vA, wB0, wB1;                // current kt staging values
    float2 nA, nB0, nB1;                // next kt
    CG_LOAD(0, vA, wB0, wB1)

    for (int kt = 0; kt < 16; ++kt) {
        As[wrA][wcA]   = vA;
        Bs[wrB0][wcB0] = wB0;
        Bs[wrB1][wcB1] = wB1;
        if (kt < 15) { CG_LOAD(kt + 1, nA, nB0, nB1) }
        __syncthreads();
#pragma unroll
        for (int kk = 0; kk < 16; ++kk) {
            float2 p = As[ty][kk];
            float2 u = Bs[kk][tx], v = Bs[kk][tx + 16];
            a00.x += p.x * u.x - p.y * u.y;  a00.y += p.x * u.y + p.y * u.x;
            a01.x += p.x * v.x - p.y * v.y;  a01.y += p.x * v.y + p.y * v.x;
        }
        __syncthreads();
        vA = nA; wB0 = nB0; wB1 = nB1;
    }
    float2* Cb = C + (size_t)c * NP;
    int gi  = i0 + ty;
    int gj0 = j0 + tx, gj1 = j0 + tx + 16;
    if (gi < M && gj0 < M) Cb[gi * M + gj0] = make_float2(a00.x * scale, a00.y * scale);
    if (gi < M && gj1 < M) Cb[gi * M + gj1] = make_float2(a01.x * scale, a01.y * scale);
}

// ---------------- S = sum u3^2 (f64 accumulate over f32 u3) ----------------
__global__ void k_sred(const float2* __restrict__ U3, double2* __restrict__ spart) {
    __shared__ double sx[256], sy[256];
    int t = threadIdx.x;
    double ax = 0.0, ay = 0.0;
    for (int i = blockIdx.x * 256 + t; i < 3 * NP; i += 64 * 256) {
        double zx = (double)U3[i].x, zy = (double)U3[i].y;
        ax += zx * zx - zy * zy;
        ay += 2.0 * zx * zy;
    }
    sx[t] = ax; sy[t] = ay;
    __syncthreads();
    for (int w = 128; w > 0; w >>= 1) {
        if (t < w) { sx[t] += sx[t + w]; sy[t] += sy[t + w]; }
        __syncthreads();
    }
    if (t == 0) spart[blockIdx.x] = make_double2(sx[0], sy[0]);
}

// ---------------- final S scalars (once, not per-thread in k_p4) ------------
__global__ void k_sfin(const double2* __restrict__ spart, double* __restrict__ sfin) {
    if (threadIdx.x != 0 || blockIdx.x != 0) return;
    double rx = 0.0, ry = 0.0;
    for (int i = 0; i < 64; ++i) { rx += spart[i].x; ry += spart[i].y; }
    double dsx = rx + 1e-7, dsy = ry;            // same association as before
    sfin[0] = dsx;
    sfin[1] = dsy;
    sfin[2] = 1.0 / (dsx * dsx + dsy * dsy);
}

// ---------------- psf -> P4 sliding-window bf16 hi/lo table -----------------
// P4[ch][di][u][t] = psf[di][u-16+t]  (u 0..303, t 0..7, zero-padded)
__global__ void k_p4(const float2* __restrict__ U3, const double* __restrict__ sfin,
                     unsigned short* __restrict__ P4) {
    int idx = blockIdx.x * 256 + threadIdx.x;
    if (idx >= P4_SIDE) return;
    double dsx = sfin[0], dsy = sfin[1], inv = sfin[2];
    int ch = idx / P4_CH, rem = idx % P4_CH;
    int di = rem / P4_DI, rem2 = rem % P4_DI;
    int u = rem2 / 8, t = rem2 % 8;
    int p = u - 16 + t;
    float v = 0.0f;
    if (di < M && p >= 0 && p < M) {
        float2 zf = U3[(ch * M + di) * M + p];
        double zx = (double)zf.x, zy = (double)zf.y;
        double zr = zx * zx - zy * zy;
        double zi = 2.0 * zx * zy;
        v = (float)((zr * dsx + zi * dsy) * inv);
    }
    unsigned short hi = f2bf(v);
    unsigned short lo = f2bf(v - bf2f(hi));
    P4[idx] = hi;
    P4[P4_SIDE + idx] = lo;
}

// ---------------- MFMA conv: banded-Toeplitz implicit GEMM ------------------
// R18/R20-exact: 4 waves, TWO 16x16 output tiles (j0, j0+16), one (ch,
// 16-di chunk); one-dloc-ahead A prefetch with sched_barrier fences;
// launch_bounds(256,2) (R19: needs the 256-VGPR budget; (256,4) spills).
// R21 lesson: LDS bank conflicts here are HIDDEN — do not swizzle (the
// XOR address math costs more than the conflicts).
// A[m=lane&15][k=8q+t] = psf[di][32c + 8q + t - m]   (window u = su0+32c)
// B[k=8q+t][n=lane&15] = img[i0+n+di-80][jT-80+32c+8q+t],  jT = j0 | j0+16
// D: row(=m/j) = 4q+reg, col(=n/i) = lane&15.
constexpr int LDS_STRIDE = 312;    // shorts; 624 B rows, 16B aligned

#define SB __builtin_amdgcn_sched_barrier(0);

#define REP9(OP) OP(0) OP(1) OP(2) OP(3) OP(4) OP(5) OP(6) OP(7) OP(8)

#define DECLA(i) short8 Ah_##i, Al_##i;
#define DECLB(i) short8 Bh_##i, Bl_##i;

#define LDA(i) Ah_##i = *(const short8*)(prH + 256 * i); \
               Al_##i = *(const short8*)(prL + 256 * i);
#define LDB(i) Bh_##i = *(const short8*)(prH + 256 * i); \
               Bl_##i = *(const short8*)(prL + 256 * i);
#define LOADA(dl) { const unsigned short* prH = pHc + (size_t)(d0 + (dl)) * P4_DI + aoff; \
                    const unsigned short* prL = pLc + (size_t)(d0 + (dl)) * P4_DI + aoff; \
                    REP9(LDA) }
#define LOADB(dl) { const unsigned short* prH = pHc + (size_t)(d0 + (dl)) * P4_DI + aoff; \
                    const unsigned short* prL = pLc + (size_t)(d0 + (dl)) * P4_DI + aoff; \
                    REP9(LDB) }

#define CMA(i) { \
    short8 bh0 = *(const short8*)&ldsI[0][rrow][32 * i + 8 * q]; \
    short8 bl0 = *(const short8*)&ldsI[1][rrow][32 * i + 8 * q]; \
    short8 bh1 = *(const short8*)&ldsI[0][rrow][32 * i + 8 * q + 16]; \
    short8 bl1 = *(const short8*)&ldsI[1][rrow][32 * i + 8 * q + 16]; \
    aHH0 = __builtin_amdgcn_mfma_f32_16x16x32_bf16(Ah_##i, bh0, aHH0, 0, 0, 0); \
    aHL0 = __builtin_amdgcn_mfma_f32_16x16x32_bf16(Ah_##i, bl0, aHL0, 0, 0, 0); \
    aLH0 = __builtin_amdgcn_mfma_f32_16x16x32_bf16(Al_##i, bh0, aLH0, 0, 0, 0); \
    aHH1 = __builtin_amdgcn_mfma_f32_16x16x32_bf16(Ah_##i, bh1, aHH1, 0, 0, 0); \
    aHL1 = __builtin_amdgcn_mfma_f32_16x16x32_bf16(Ah_##i, bl1, aHL1, 0, 0, 0); \
    aLH1 = __builtin_amdgcn_mfma_f32_16x16x32_bf16(Al_##i, bh1, aLH1, 0, 0, 0); }
#define CMB(i) { \
    short8 bh0 = *(const short8*)&ldsI[0][rrow][32 * i + 8 * q]; \
    short8 bl0 = *(const short8*)&ldsI[1][rrow][32 * i + 8 * q]; \
    short8 bh1 = *(const short8*)&ldsI[0][rrow][32 * i + 8 * q + 16]; \
    short8 bl1 = *(const short8*)&ldsI[1][rrow][32 * i + 8 * q + 16]; \
    aHH0 = __builtin_amdgcn_mfma_f32_16x16x32_bf16(Bh_##i, bh0, aHH0, 0, 0, 0); \
    aHL0 = __builtin_amdgcn_mfma_f32_16x16x32_bf16(Bh_##i, bl0, aHL0, 0, 0, 0); \
    aLH0 = __builtin_amdgcn_mfma_f32_16x16x32_bf16(Bl_##i, bh0, aLH0, 0, 0, 0); \
    aHH1 = __builtin_amdgcn_mfma_f32_16x16x32_bf16(Bh_##i, bh1, aHH1, 0, 0, 0); \
    aHL1 = __builtin_amdgcn_mfma_f32_16x16x32_bf16(Bh_##i, bl1, aHL1, 0, 0, 0); \
    aLH1 = __builtin_amdgcn_mfma_f32_16x16x32_bf16(Bl_##i, bh1, aLH1, 0, 0, 0); }
#define COMPA(dl) { int rrow = ln + (dl); REP9(CMA) }
#define COMPB(dl) { int rrow = ln + (dl); REP9(CMB) }

__global__ __launch_bounds__(256, 2)
void k_conv(const unsigned short* __restrict__ IMG2,
            const unsigned short* __restrict__ P4,
            float* __restrict__ PART) {
    __shared__ __align__(16) unsigned short ldsI[2][31][LDS_STRIDE];

    int tid  = threadIdx.x;
    int w    = tid >> 6;           // wave 0..3
    int lane = tid & 63;
    int ln   = lane & 15;          // m for A, n for B/C-col
    int q    = lane >> 4;          // 0..3
    int j0 = blockIdx.x * 32;      // TWO 16-col tiles: j0 and j0+16
    int i0 = blockIdx.y * 16;
    int bz = blockIdx.z;           // ch*16 + chunk
    int ch = bz >> 4, chunk = bz & 15;
    int d0 = chunk << 4;

    const unsigned short* imgH = IMG2 + ch * IMG_CH;
    const unsigned short* imgL = imgH + IMG_SIDE;
    const unsigned short* pHc  = P4 + ch * P4_CH;
    const unsigned short* pLc  = pHc + P4_SIDE;

    // sliding-window index: u = su0 + 32*cc, su0 = 16 + 8q - ln in 1..40
    int su0  = 16 + 8 * q - ln;
    int aoff = su0 * 8;                    // shorts; + 256 per cc step

    f32x4 aHH0 = {0.f,0.f,0.f,0.f}, aHL0 = {0.f,0.f,0.f,0.f}, aLH0 = {0.f,0.f,0.f,0.f};
    f32x4 aHH1 = {0.f,0.f,0.f,0.f}, aHL1 = {0.f,0.f,0.f,0.f}, aLH1 = {0.f,0.f,0.f,0.f};

    REP9(DECLA)
    REP9(DECLB)

    int dbase = 4 * w;
    LOADA(dbase + 0)               // in flight during staging

    // ---- stage image tile: rows i0+d0 .. +30, cols j0 .. j0+303, hi+lo ----
    int row0 = i0 + d0;
    for (int idx = tid; idx < 2 * 31 * 38; idx += 256) {
        int plane = idx / (31 * 38);
        int rem = idx - plane * (31 * 38);
        int r = rem / 38, c = rem - r * 38;
        const unsigned short* src =
            (plane ? imgL : imgH) + (size_t)(row0 + r) * IMG_COLS + j0 + c * 8;
        *(short8*)&ldsI[plane][r][c * 8] = *(const short8*)src;
    }
    __syncthreads();

    LOADB(dbase + 1)
    SB
    COMPA(dbase + 0)
    SB
    LOADA(dbase + 2)
    SB
    COMPB(dbase + 1)
    SB
    LOADB(dbase + 3)
    SB
    COMPA(dbase + 2)
    SB
    COMPB(dbase + 3)

    // ---- combine the three precision terms, then reduce across the 4 waves
    f32x4 tot0, tot1;
#pragma unroll
    for (int r = 0; r < 4; ++r) {
        tot0[r] = aHH0[r] + aHL0[r] + aLH0[r];
        tot1[r] = aHH1[r] + aHL1[r] + aLH1[r];
    }

    __syncthreads();                       // everyone done reading image LDS
    float* red = (float*)&ldsI[0][0][0];
    if (w) {
#pragma unroll
        for (int r = 0; r < 4; ++r) {
            red[((w - 1) * 64 + lane) * 8 + r]     = tot0[r];
            red[((w - 1) * 64 + lane) * 8 + 4 + r] = tot1[r];
        }
    }
    __syncthreads();
    if (w == 0) {
#pragma unroll
        for (int wv = 0; wv < 3; ++wv)
#pragma unroll
            for (int r = 0; r < 4; ++r) {
                tot0[r] += red[(wv * 64 + lane) * 8 + r];
                tot1[r] += red[(wv * 64 + lane) * 8 + 4 + r];
            }
        // D row = 4q+reg -> j = jT+4q+reg ; D col = ln -> i = i0+ln
        float* op = PART + (size_t)bz * (RESO * RESO) + (i0 + ln) * RESO + j0 + 4 * q;
        float4 o0; o0.x = tot0[0]; o0.y = tot0[1]; o0.z = tot0[2]; o0.w = tot0[3];
        float4 o1; o1.x = tot1[0]; o1.y = tot1[1]; o1.z = tot1[2]; o1.w = tot1[3];
        *(float4*)op = o0;
        *(float4*)(op + 16) = o1;
    }
}

// ---------------- reduce partials + clip + layout (i,j,c) ----------------
__global__ void k_out(const float* __restrict__ PART, float* __restrict__ out) {
    int idx = blockIdx.x * 256 + threadIdx.x;
    if (idx >= 3 * RESO * RESO) return;
    int c = idx / (RESO * RESO), ij = idx % (RESO * RESO);
    float s = 0.0f;
    for (int kz = 0; kz < 16; ++kz)
        s += PART[(size_t)(c * 16 + kz) * (RESO * RESO) + ij];
    s = fminf(fmaxf(s, 0.0f), 1.0f);
    int i = ij / RESO, j = ij % RESO;
    out[(i * RESO + j) * 3 + c] = s;
}

// ---------------------------------------------------------------------------
extern "C" void kernel_launch(void* const* d_in, const int* in_sizes, int n_in,
                              void* d_out, int out_size, void* d_ws, size_t ws_size,
                              hipStream_t stream) {
    const float* image = (const float*)d_in[0];   // (255,255,3)
    const float* depth = (const float*)d_in[1];   // (255,255)
    float* out = (float*)d_out;                   // (160,160,3)

    // workspace carve (256B aligned), ~28 MB
    char* p = (char*)d_ws;
    auto alloc = [&](size_t bytes) { void* r = (void*)p; p += (bytes + 255) & ~(size_t)255; return r; };
    float*   meanp = (float*)alloc(4);
    float*   mval  = (float*)alloc(MAXN * 4);
    double*  sfin  = (double*)alloc(3 * 8);
    float2*  wtab  = (float2*)alloc((size_t)M * 8);
    float2*  Wf    = (float2*)alloc((size_t)NP * 8);
    float2*  UH    = (float2*)alloc((size_t)6 * NP * 8);   // U2 | Hb
    float2*  Td    = (float2*)alloc((size_t)6 * NP * 8);
    float2*  EF    = (float2*)alloc((size_t)6 * NP * 8);   // FU | FH
    float2*  U3    = (float2*)alloc((size_t)3 * NP * 8);
    double2* spart = (double2*)alloc(64 * 16);
    unsigned short* P4   = (unsigned short*)alloc((size_t)2 * P4_SIDE * 2);
    unsigned short* IMG2 = (unsigned short*)alloc((size_t)2 * IMG_SIDE * 2);
    float*   PART  = (float*)alloc((size_t)48 * RESO * RESO * 4);

    float2* U2 = UH;
    float2* Hb = UH + (size_t)3 * NP;

    // exact python-f64 scalar path
    double dx = 0.002 / 255.0;
    double Lx = dx * 255.0;
    double ap = (Lx / 2.0) * 0.1 + 1e-7;
    float ap_f = (float)ap;

    double xstart = -(Lx / 2.0);
    double xstop  =  Lx / 2.0;
    double xstep  = (xstop - xstart) / 254.0;
    double fstart = -1.0 / (2.0 * dx);
    double fstop  =  1.0 / (2.0 * dx);
    double fstep  = (fstop - fstart) / 254.0;

    k_wtab<<<1, 256, 0, stream>>>(wtab);
    k_mleaf<<<(PW.nNode + 255) / 256, 256, 0, stream>>>(depth, mval);
    k_mtree<<<1, 256, 0, stream>>>(depth, mval, meanp);
    int gprep = (4 * NP + IMG_SIDE + 255) / 256;   // 3201
    k_prep<<<gprep, 256, 0, stream>>>(image, IMG2, Wf, wtab, U2, Hb, meanp,
                                      xstart, xstep, xstop,
                                      fstart, fstep, fstop, ap_f);

    dim3 bb(256);
    k_cgemm<<<dim3(8, 16, 6), bb, 0, stream>>>(Wf, 0, UH, nullptr, NP, Td, 0, 0, 1.0f);
    k_cgemm<<<dim3(8, 16, 6), bb, 0, stream>>>(Td, NP, Wf, nullptr, 0, EF, 0, 0, 1.0f);
    k_cgemm<<<dim3(8, 16, 3), bb, 0, stream>>>(Wf, 0, EF + (size_t)3 * NP, EF, NP,
                                               Td, 1, 0, 1.0f / 255.0f);
    k_cgemm<<<dim3(8, 16, 3), bb, 0, stream>>>(Td, NP, Wf, nullptr, 0, U3, 0, 1,
                                               1.0f / 255.0f);

    k_sred<<<64, 256, 0, stream>>>(U3, spart);
    k_sfin<<<1, 64, 0, stream>>>(spart, sfin);
    k_p4<<<(P4_SIDE + 255) / 256, 256, 0, stream>>>(U3, sfin, P4);

    k_conv<<<dim3(5, 10, 48), 256, 0, stream>>>(IMG2, P4, PART);
    k_out<<<300, 256, 0, stream>>>(PART, out);
}

// Round 14
// 249.587 us; speedup vs baseline: 1.2361x; 1.0201x over previous
//
#include <hip/hip_runtime.h>
#include <hip/hip_bf16.h>
#include <math.h>

// ---------------------------------------------------------------------------
// MjCambrianOptics. Correctness-critical (R7-validated, DO NOT TOUCH):
//   * mean(depth) = numpy BUFFERED reduce: seed a[0], then sequential
//     += pairwise_sum(8192-chunk), 128-leaf/8-acc recursion.
//   * ki = fl32(2pi)/fl32(wl) f32 divide; linspace f64-cast; th/ph op order.
// R11: conv -> MFMA (banded-Toeplitz implicit GEMM, split-bf16 hi/lo).
// R17: sliding-window P4 => coalesced A-loads. 162->82 us (CONFIRMED).
// R18: two j-tiles/block (A reuse). 82->55.6.
// R19: FAILED (256,4) VGPR cap -> spill. 2 blocks/CU is a HARD constraint.
// R20: (256,2) + 16x32 cgemm 128-blocks/plane. tot 252.7 (best).
// R21/R22: cgemm micro-tuning regressed (hidden conflicts / serial prefetch
//      chains). R20's cgemm is a local optimum — left alone.
// R24: W-table neutral -> trig was never the cost. Reverted.
// R25: (a) k_conv 2x2 tiles (i0/i0+16 x j0/j0+16): same A regs feed 12
//      MFMAs, A traffic halves again; LDS [2][47][312]=57.3KB, grid (5,5,48).
//      (b) k_sfin fused into k_p4 (lane0/block, same summation order).
//      (c) k_wtab dropped. 11 launches (was 13). All bit-identical.
// ---------------------------------------------------------------------------

constexpr int M   = 255;
constexpr int NP  = M * M;        // 65025
constexpr int RESO = 160;

// IMG2 (padded bf16 image, hi|lo): [side][ch][row 0..415][col 0..447]
constexpr int IMG_ROWS = 416, IMG_COLS = 448;
constexpr int IMG_CH   = IMG_ROWS * IMG_COLS;      // 186368
constexpr int IMG_SIDE = 3 * IMG_CH;               // 559104
// P4 sliding-window table (bf16 hi|lo): [side][ch][di 0..255][u 0..303][t 0..7]
// entry (di,u,t) = psf[di][u-16+t], zero-padded outside [0,M)
constexpr int P4_DI   = 304 * 8;                   // 2432 shorts per di
constexpr int P4_CH   = 256 * P4_DI;               // 622592
constexpr int P4_SIDE = 3 * P4_CH;                 // 1867776

typedef __attribute__((ext_vector_type(8))) short short8;
typedef __attribute__((ext_vector_type(4))) float f32x4;

__device__ __forceinline__ unsigned short f2bf(float f) {
    unsigned int u = __float_as_uint(f);
    unsigned int r = (u + 0x7fffu + ((u >> 16) & 1u)) >> 16;
    return (unsigned short)r;
}
__device__ __forceinline__ float bf2f(unsigned short h) {
    return __uint_as_float(((unsigned int)h) << 16);
}

// ---------------- numpy buffered-reduce pairwise forest (compile-time) ------
constexpr int MAXN = 1100;
struct PWForest {
    int kind[MAXN];
    int off[MAXN], len[MAXN];
    int li[MAXN], ri[MAXN];
    int lvl[MAXN];
    int nNode, nLeaf, maxLvl;
    int roots[16], nRoots;
};
constexpr int pwf_build(PWForest& T, int o, int n) {
    if (n <= 128) {
        int id = T.nNode++;
        T.kind[id] = 0; T.off[id] = o; T.len[id] = n;
        T.lvl[id] = 0; T.nLeaf++;
        return id;
    }
    int n2 = (n / 2) - ((n / 2) % 8);
    int a = pwf_build(T, o, n2);
    int b = pwf_build(T, o + n2, n - n2);
    int id = T.nNode++;
    T.kind[id] = 1; T.li[id] = a; T.ri[id] = b;
    int l = (T.lvl[a] > T.lvl[b] ? T.lvl[a] : T.lvl[b]) + 1;
    T.lvl[id] = l; if (l > T.maxLvl) T.maxLvl = l;
    return id;
}
constexpr PWForest pwf_make() {
    PWForest T{};
    int pos = 1, rem = NP - 1;            // reduce seeds with a[0]
    while (rem > 0) {
        int c = rem > 8192 ? 8192 : rem;  // nditer buffer = 8192 elements
        T.roots[T.nRoots++] = pwf_build(T, pos, c);
        pos += c; rem -= c;
    }
    return T;
}
constexpr PWForest PW = pwf_make();
static_assert(PW.nNode <= MAXN, "forest overflow");
static_assert(PW.nRoots == 8, "chunk count");

// leaves are independent: one THREAD per node id, exact per-leaf arithmetic
__global__ void k_mleaf(const float* __restrict__ depth, float* __restrict__ val) {
    int id = blockIdx.x * 256 + threadIdx.x;
    if (id >= PW.nNode || PW.kind[id] != 0) return;
    const float* a = depth + PW.off[id];
    int n = PW.len[id];
    float r0 = a[0], r1 = a[1], r2 = a[2], r3 = a[3];
    float r4 = a[4], r5 = a[5], r6 = a[6], r7 = a[7];
    int lim = n - (n % 8);
    int i = 8;
    for (; i < lim; i += 8) {
        r0 += a[i + 0]; r1 += a[i + 1]; r2 += a[i + 2]; r3 += a[i + 3];
        r4 += a[i + 4]; r5 += a[i + 5]; r6 += a[i + 6]; r7 += a[i + 7];
    }
    float res = ((r0 + r1) + (r2 + r3)) + ((r4 + r5) + (r6 + r7));
    for (; i < n; ++i) res += a[i];
    val[id] = res;
}

// internal levels + root chain, single block (exact same order as before)
__global__ void k_mtree(const float* __restrict__ depth, float* __restrict__ val,
                        float* __restrict__ meanp) {
    int tid = threadIdx.x;
    for (int l = 1; l <= PW.maxLvl; ++l) {
        for (int id = tid; id < PW.nNode; id += 256)
            if (PW.kind[id] == 1 && PW.lvl[id] == l)
                val[id] = val[PW.li[id]] + val[PW.ri[id]];
        __syncthreads();
    }
    if (tid == 0) {
        float io1 = depth[0];
        for (int r = 0; r < PW.nRoots; ++r)
            io1 = io1 + val[PW.roots[r]];
        meanp[0] = io1 / 65025.0f;
    }
}

// ---------------- prep: u2H fields + DFT W + padded bf16 image --------------
__global__ void k_prep(const float* __restrict__ img, unsigned short* __restrict__ IMG2,
                       float2* __restrict__ W,
                       float2* __restrict__ U2, float2* __restrict__ Hb,
                       const float* __restrict__ meanp,
                       double xstart, double xstep, double xstop,
                       double fstart, double fstep, double fstop,
                       float ap_f) {
#pragma clang fp contract(off)
    int idx = blockIdx.x * 256 + threadIdx.x;
    if (idx < 3 * NP) {
        int c = idx / NP, ij = idx % NP, i = ij / M, j = ij % M;
        const float wls[3] = {6.1e-07f, 5.3e-07f, 4.7e-07f};
        float wl = wls[c];
        float ki = ((float)6.283185307179586) / wl;
        float d  = meanp[0];
        float d2 = d * d;

        float x  = (i == 254) ? (float)xstop : (float)((double)i * xstep + xstart);
        float y  = (j == 254) ? (float)xstop : (float)((double)j * xstep + xstart);
        float fx = (i == 254) ? (float)fstop : (float)((double)i * fstep + fstart);
        float fy = (j == 254) ? (float)fstop : (float)((double)j * fstep + fstart);

        float xx = x * x, yy = y * y;
        float X1Y1 = xx + yy;

        float s  = sqrtf(X1Y1 + d2);
        float th = ki * s;
        float A  = (sqrtf(X1Y1) / ap_f <= 1.0f) ? 1.0f : 0.0f;
        float2 u2v;
        if (A != 0.0f) u2v = make_float2((float)cos((double)th), (float)sin((double)th));
        else           u2v = make_float2(0.0f, 0.0f);

        float a = wl * fx, b = wl * fy;
        float arg = (1.0f - a * a) - b * b;
        float FXY = sqrtf(fmaxf(arg, 0.0f));
        float Hv  = (sqrtf(fx * fx + fy * fy) < (1.0f / wl)) ? 1.0f : 0.0f;
        float kd  = ki * d;
        float ph  = kd * FXY;
        float cph = (float)cos((double)ph), sph = (float)sin((double)ph);
        float2 hv = make_float2(Hv * cph, Hv * sph);

        U2[idx] = u2v;
        Hb[idx] = hv;
        return;
    }
    if (idx < 4 * NP) {
        int e = idx - 3 * NP;
        int n = e / M, k = e % M;
        int m = (n * k) % M;
        double ang = -2.0 * 3.14159265358979323846 * (double)m / 255.0;
        W[e] = make_float2((float)cos(ang), (float)sin(ang));
        return;
    }
    int e = idx - 4 * NP;
    if (e >= IMG_SIDE) return;
    int ch = e / IMG_CH, rem = e % IMG_CH;
    int prow = rem / IMG_COLS, pcol = rem % IMG_COLS;
    int a = prow - 80, b = pcol - 80;
    float v = 0.0f;
    if (a >= 0 && a < M && b >= 0 && b < M) v = img[(a * M + b) * 3 + ch];
    unsigned short hi = f2bf(v);
    unsigned short lo = f2bf(v - bf2f(hi));
    IMG2[e] = hi;
    IMG2[IMG_SIDE + e] = lo;
}

// ---------------- batched f32 complex GEMM, 16x32 tile, 2/thread ------------
// R20-exact: 128 blocks/plane. Per-output K accumulation sequence unchanged
// (same kt/kk order, same FMA expressions) -> bit-identical.
// One-kt-ahead register prefetch (1 A + 2 B float2 scalars).
#define CG_LOAD(KT, VA, WB0, WB1) { \
    int k0_ = (KT) * 16; \
    { int r_ = threadIdx.x >> 4, c_ = threadIdx.x & 15; \
      int gi_ = i0 + r_, gk_ = k0_ + c_; \
      VA = (gi_ < M && gk_ < M) ? Ab[gi_ * M + gk_] : make_float2(0.f, 0.f); \
      if (conjA) VA.y = -VA.y; } \
    { int r2_ = threadIdx.x >> 5, c2_ = threadIdx.x & 31; \
      int gk2_ = k0_ + r2_, gj_ = j0 + c2_; \
      WB0 = make_float2(0.f, 0.f); \
      if (gk2_ < M && gj_ < M) { \
          WB0 = Bb[gk2_ * M + gj_]; \
          if (B2b) { float2 z_ = B2b[gk2_ * M + gj_]; \
              WB0 = make_float2(WB0.x * z_.x - WB0.y * z_.y, WB0.x * z_.y + WB0.y * z_.x); } \
      } \
      if (conjB) WB0.y = -WB0.y; } \
    { int idx_ = threadIdx.x + 256; \
      int r2_ = idx_ >> 5, c2_ = idx_ & 31; \
      int gk2_ = k0_ + r2_, gj_ = j0 + c2_; \
      WB1 = make_float2(0.f, 0.f); \
      if (gk2_ < M && gj_ < M) { \
          WB1 = Bb[gk2_ * M + gj_]; \
          if (B2b) { float2 z_ = B2b[gk2_ * M + gj_]; \
              WB1 = make_float2(WB1.x * z_.x - WB1.y * z_.y, WB1.x * z_.y + WB1.y * z_.x); } \
      } \
      if (conjB) WB1.y = -WB1.y; } }

__global__ __launch_bounds__(256)
void k_cgemm(const float2* __restrict__ A, int aBatch,
             const float2* __restrict__ B, const float2* __restrict__ B2,
             int bBatch, float2* __restrict__ C,
             int conjA, int conjB, float scale) {
    __shared__ float2 As[16][17];
    __shared__ float2 Bs[16][33];
    int c = blockIdx.z;
    int tx = threadIdx.x & 15, ty = threadIdx.x >> 4;
    int i0 = blockIdx.y * 16, j0 = blockIdx.x * 32;
    const float2* Ab = A + (size_t)c * aBatch;
    const float2* Bb = B + (size_t)c * bBatch;
    const float2* B2b = B2 ? (B2 + (size_t)c * bBatch) : nullptr;
    float2 a00 = {0,0}, a01 = {0,0};

    int wrA  = threadIdx.x >> 4,  wcA  = threadIdx.x & 15;
    int wrB0 = threadIdx.x >> 5,  wcB0 = threadIdx.x & 31;
    int wrB1 = (threadIdx.x + 256) >> 5, wcB1 = (threadIdx.x + 256) & 31;

    float2 vA, wB0, wB1;                // current kt staging values
    float2 nA, nB0, nB1;                // next kt
    CG_LOAD(0, vA, wB0, wB1)

    for (int kt = 0; kt < 16; ++kt) {
        As[wrA][wcA]   = vA;
        Bs[wrB0][wcB0] = wB0;
        Bs[wrB1][wcB1] = wB1;
        if (kt < 15) { CG_LOAD(kt + 1, nA, nB0, nB1) }
        __syncthreads();
#pragma unroll
        for (int kk = 0; kk < 16; ++kk) {
            float2 p = As[ty][kk];
            float2 u = Bs[kk][tx], v = Bs[kk][tx + 16];
            a00.x += p.x * u.x - p.y * u.y;  a00.y += p.x * u.y + p.y * u.x;
            a01.x += p.x * v.x - p.y * v.y;  a01.y += p.x * v.y + p.y * v.x;
        }
        __syncthreads();
        vA = nA; wB0 = nB0; wB1 = nB1;
    }
    float2* Cb = C + (size_t)c * NP;
    int gi  = i0 + ty;
    int gj0 = j0 + tx, gj1 = j0 + tx + 16;
    if (gi < M && gj0 < M) Cb[gi * M + gj0] = make_float2(a00.x * scale, a00.y * scale);
    if (gi < M && gj1 < M) Cb[gi * M + gj1] = make_float2(a01.x * scale, a01.y * scale);
}

// ---------------- S = sum u3^2 (f64 accumulate over f32 u3) ----------------
__global__ void k_sred(const float2* __restrict__ U3, double2* __restrict__ spart) {
    __shared__ double sx[256], sy[256];
    int t = threadIdx.x;
    double ax = 0.0, ay = 0.0;
    for (int i = blockIdx.x * 256 + t; i < 3 * NP; i += 64 * 256) {
        double zx = (double)U3[i].x, zy = (double)U3[i].y;
        ax += zx * zx - zy * zy;
        ay += 2.0 * zx * zy;
    }
    sx[t] = ax; sy[t] = ay;
    __syncthreads();
    for (int w = 128; w > 0; w >>= 1) {
        if (t < w) { sx[t] += sx[t + w]; sy[t] += sy[t + w]; }
        __syncthreads();
    }
    if (t == 0) spart[blockIdx.x] = make_double2(sx[0], sy[0]);
}

// ---------------- psf -> P4 sliding-window bf16 hi/lo table -----------------
// P4[ch][di][u][t] = psf[di][u-16+t]  (u 0..303, t 0..7, zero-padded)
// R25: spart finalization fused in (lane 0 per block, exact same sum order).
__global__ void k_p4(const float2* __restrict__ U3, const double2* __restrict__ spart,
                     unsigned short* __restrict__ P4) {
    __shared__ double sh[3];
    if (threadIdx.x == 0) {
        double rx = 0.0, ry = 0.0;
        for (int i = 0; i < 64; ++i) { rx += spart[i].x; ry += spart[i].y; }
        double dsx_ = rx + 1e-7, dsy_ = ry;      // same association as before
        sh[0] = dsx_; sh[1] = dsy_;
        sh[2] = 1.0 / (dsx_ * dsx_ + dsy_ * dsy_);
    }
    __syncthreads();
    int idx = blockIdx.x * 256 + threadIdx.x;
    if (idx >= P4_SIDE) return;
    double dsx = sh[0], dsy = sh[1], inv = sh[2];
    int ch = idx / P4_CH, rem = idx % P4_CH;
    int di = rem / P4_DI, rem2 = rem % P4_DI;
    int u = rem2 / 8, t = rem2 % 8;
    int p = u - 16 + t;
    float v = 0.0f;
    if (di < M && p >= 0 && p < M) {
        float2 zf = U3[(ch * M + di) * M + p];
        double zx = (double)zf.x, zy = (double)zf.y;
        double zr = zx * zx - zy * zy;
        double zi = 2.0 * zx * zy;
        v = (float)((zr * dsx + zi * dsy) * inv);
    }
    unsigned short hi = f2bf(v);
    unsigned short lo = f2bf(v - bf2f(hi));
    P4[idx] = hi;
    P4[P4_SIDE + idx] = lo;
}

// ---------------- MFMA conv: banded-Toeplitz implicit GEMM ------------------
// R25: 4 waves, FOUR 16x16 output tiles (i0/i0+16 x j0/j0+16), one (ch,
// 16-di chunk). A registers (independent of i AND j) feed 12 MFMA per
// fragment. Image tile 47 rows x 304 cols (hi+lo) in stride-312 LDS
// (57.3 KB). One-dloc-ahead A prefetch with sched_barrier fences;
// launch_bounds(256,2) (R19: needs the 256-VGPR budget).
// R21 lesson: LDS bank conflicts here are HIDDEN — do not swizzle.
// A[m=lane&15][k=8q+t] = psf[di][32c + 8q + t - m]   (window u = su0+32c)
// B[k=8q+t][n=lane&15] = img[iT+n+di-80][jT-80+32c+8q+t], iT=i0|i0+16, jT=j0|j0+16
// D: row(=m/j) = 4q+reg, col(=n/i) = lane&15.
constexpr int LDS_STRIDE = 312;    // shorts; 624 B rows, 16B aligned

#define SB __builtin_amdgcn_sched_barrier(0);

#define REP9(OP) OP(0) OP(1) OP(2) OP(3) OP(4) OP(5) OP(6) OP(7) OP(8)

#define DECLA(i) short8 Ah_##i, Al_##i;
#define DECLB(i) short8 Bh_##i, Bl_##i;

#define LDA(i) Ah_##i = *(const short8*)(prH + 256 * i); \
               Al_##i = *(const short8*)(prL + 256 * i);
#define LDB(i) Bh_##i = *(const short8*)(prH + 256 * i); \
               Bl_##i = *(const short8*)(prL + 256 * i);
#define LOADA(dl) { const unsigned short* prH = pHc + (size_t)(d0 + (dl)) * P4_DI + aoff; \
                    const unsigned short* prL = pLc + (size_t)(d0 + (dl)) * P4_DI + aoff; \
                    REP9(LDA) }
#define LOADB(dl) { const unsigned short* prH = pHc + (size_t)(d0 + (dl)) * P4_DI + aoff; \
                    const unsigned short* prL = pLc + (size_t)(d0 + (dl)) * P4_DI + aoff; \
                    REP9(LDB) }

#define CMBODY(AH, AL) { \
    short8 bh00 = *(const short8*)&ldsI[0][rrow][colb]; \
    short8 bl00 = *(const short8*)&ldsI[1][rrow][colb]; \
    short8 bh01 = *(const short8*)&ldsI[0][rrow][colb + 16]; \
    short8 bl01 = *(const short8*)&ldsI[1][rrow][colb + 16]; \
    short8 bh10 = *(const short8*)&ldsI[0][rrow + 16][colb]; \
    short8 bl10 = *(const short8*)&ldsI[1][rrow + 16][colb]; \
    short8 bh11 = *(const short8*)&ldsI[0][rrow + 16][colb + 16]; \
    short8 bl11 = *(const short8*)&ldsI[1][rrow + 16][colb + 16]; \
    aHH00 = __builtin_amdgcn_mfma_f32_16x16x32_bf16(AH, bh00, aHH00, 0, 0, 0); \
    aHL00 = __builtin_amdgcn_mfma_f32_16x16x32_bf16(AH, bl00, aHL00, 0, 0, 0); \
    aLH00 = __builtin_amdgcn_mfma_f32_16x16x32_bf16(AL, bh00, aLH00, 0, 0, 0); \
    aHH01 = __builtin_amdgcn_mfma_f32_16x16x32_bf16(AH, bh01, aHH01, 0, 0, 0); \
    aHL01 = __builtin_amdgcn_mfma_f32_16x16x32_bf16(AH, bl01, aHL01, 0, 0, 0); \
    aLH01 = __builtin_amdgcn_mfma_f32_16x16x32_bf16(AL, bh01, aLH01, 0, 0, 0); \
    aHH10 = __builtin_amdgcn_mfma_f32_16x16x32_bf16(AH, bh10, aHH10, 0, 0, 0); \
    aHL10 = __builtin_amdgcn_mfma_f32_16x16x32_bf16(AH, bl10, aHL10, 0, 0, 0); \
    aLH10 = __builtin_amdgcn_mfma_f32_16x16x32_bf16(AL, bh10, aLH10, 0, 0, 0); \
    aHH11 = __builtin_amdgcn_mfma_f32_16x16x32_bf16(AH, bh11, aHH11, 0, 0, 0); \
    aHL11 = __builtin_amdgcn_mfma_f32_16x16x32_bf16(AH, bl11, aHL11, 0, 0, 0); \
    aLH11 = __builtin_amdgcn_mfma_f32_16x16x32_bf16(AL, bh11, aLH11, 0, 0, 0); }

#define CMA(i) { int colb = 32 * i + 8 * q; CMBODY(Ah_##i, Al_##i) }
#define CMB(i) { int colb = 32 * i + 8 * q; CMBODY(Bh_##i, Bl_##i) }
#define COMPA(dl) { int rrow = ln + (dl); REP9(CMA) }
#define COMPB(dl) { int rrow = ln + (dl); REP9(CMB) }

__global__ __launch_bounds__(256, 2)
void k_conv(const unsigned short* __restrict__ IMG2,
            const unsigned short* __restrict__ P4,
            float* __restrict__ PART) {
    __shared__ __align__(16) unsigned short ldsI[2][47][LDS_STRIDE];

    int tid  = threadIdx.x;
    int w    = tid >> 6;           // wave 0..3
    int lane = tid & 63;
    int ln   = lane & 15;          // m for A, n for B/C-col
    int q    = lane >> 4;          // 0..3
    int j0 = blockIdx.x * 32;      // j-tiles j0, j0+16
    int i0 = blockIdx.y * 32;      // i-tiles i0, i0+16
    int bz = blockIdx.z;           // ch*16 + chunk
    int ch = bz >> 4, chunk = bz & 15;
    int d0 = chunk << 4;

    const unsigned short* imgH = IMG2 + ch * IMG_CH;
    const unsigned short* imgL = imgH + IMG_SIDE;
    const unsigned short* pHc  = P4 + ch * P4_CH;
    const unsigned short* pLc  = pHc + P4_SIDE;

    // sliding-window index: u = su0 + 32*cc, su0 = 16 + 8q - ln in 1..40
    int su0  = 16 + 8 * q - ln;
    int aoff = su0 * 8;                    // shorts; + 256 per cc step

    f32x4 aHH00 = {0,0,0,0}, aHL00 = {0,0,0,0}, aLH00 = {0,0,0,0};
    f32x4 aHH01 = {0,0,0,0}, aHL01 = {0,0,0,0}, aLH01 = {0,0,0,0};
    f32x4 aHH10 = {0,0,0,0}, aHL10 = {0,0,0,0}, aLH10 = {0,0,0,0};
    f32x4 aHH11 = {0,0,0,0}, aHL11 = {0,0,0,0}, aLH11 = {0,0,0,0};

    REP9(DECLA)
    REP9(DECLB)

    int dbase = 4 * w;
    LOADA(dbase + 0)               // in flight during staging

    // ---- stage image tile: rows i0+d0 .. +46, cols j0 .. j0+303, hi+lo ----
    int row0 = i0 + d0;
    for (int idx = tid; idx < 2 * 47 * 38; idx += 256) {
        int plane = idx / (47 * 38);
        int rem = idx - plane * (47 * 38);
        int r = rem / 38, c = rem - r * 38;
        const unsigned short* src =
            (plane ? imgL : imgH) + (size_t)(row0 + r) * IMG_COLS + j0 + c * 8;
        *(short8*)&ldsI[plane][r][c * 8] = *(const short8*)src;
    }
    __syncthreads();

    LOADB(dbase + 1)
    SB
    COMPA(dbase + 0)
    SB
    LOADA(dbase + 2)
    SB
    COMPB(dbase + 1)
    SB
    LOADB(dbase + 3)
    SB
    COMPA(dbase + 2)
    SB
    COMPB(dbase + 3)

    // ---- combine the three precision terms, then reduce across the 4 waves
    f32x4 tot00, tot01, tot10, tot11;
#pragma unroll
    for (int r = 0; r < 4; ++r) {
        tot00[r] = aHH00[r] + aHL00[r] + aLH00[r];
        tot01[r] = aHH01[r] + aHL01[r] + aLH01[r];
        tot10[r] = aHH10[r] + aHL10[r] + aLH10[r];
        tot11[r] = aHH11[r] + aHL11[r] + aLH11[r];
    }

    __syncthreads();                       // everyone done reading image LDS
    float* red = (float*)&ldsI[0][0][0];
    if (w) {
#pragma unroll
        for (int r = 0; r < 4; ++r) {
            int base = ((w - 1) * 64 + lane) * 16;
            red[base + r]      = tot00[r];
            red[base + 4 + r]  = tot01[r];
            red[base + 8 + r]  = tot10[r];
            red[base + 12 + r] = tot11[r];
        }
    }
    __syncthreads();
    if (w == 0) {
#pragma unroll
        for (int wv = 0; wv < 3; ++wv)
#pragma unroll
            for (int r = 0; r < 4; ++r) {
                int base = (wv * 64 + lane) * 16;
                tot00[r] += red[base + r];
                tot01[r] += red[base + 4 + r];
                tot10[r] += red[base + 8 + r];
                tot11[r] += red[base + 12 + r];
            }
        // D row = 4q+reg -> j = jT+4q+reg ; D col = ln -> i = iT+ln
        float* op0 = PART + (size_t)bz * (RESO * RESO) + (i0 + ln) * RESO + j0 + 4 * q;
        float* op1 = PART + (size_t)bz * (RESO * RESO) + (i0 + 16 + ln) * RESO + j0 + 4 * q;
        float4 o;
        o.x = tot00[0]; o.y = tot00[1]; o.z = tot00[2]; o.w = tot00[3];
        *(float4*)op0 = o;
        o.x = tot01[0]; o.y = tot01[1]; o.z = tot01[2]; o.w = tot01[3];
        *(float4*)(op0 + 16) = o;
        o.x = tot10[0]; o.y = tot10[1]; o.z = tot10[2]; o.w = tot10[3];
        *(float4*)op1 = o;
        o.x = tot11[0]; o.y = tot11[1]; o.z = tot11[2]; o.w = tot11[3];
        *(float4*)(op1 + 16) = o;
    }
}

// ---------------- reduce partials + clip + layout (i,j,c) ----------------
__global__ void k_out(const float* __restrict__ PART, float* __restrict__ out) {
    int idx = blockIdx.x * 256 + threadIdx.x;
    if (idx >= 3 * RESO * RESO) return;
    int c = idx / (RESO * RESO), ij = idx % (RESO * RESO);
    float s = 0.0f;
    for (int kz = 0; kz < 16; ++kz)
        s += PART[(size_t)(c * 16 + kz) * (RESO * RESO) + ij];
    s = fminf(fmaxf(s, 0.0f), 1.0f);
    int i = ij / RESO, j = ij % RESO;
    out[(i * RESO + j) * 3 + c] = s;
}

// ---------------------------------------------------------------------------
extern "C" void kernel_launch(void* const* d_in, const int* in_sizes, int n_in,
                              void* d_out, int out_size, void* d_ws, size_t ws_size,
                              hipStream_t stream) {
    const float* image = (const float*)d_in[0];   // (255,255,3)
    const float* depth = (const float*)d_in[1];   // (255,255)
    float* out = (float*)d_out;                   // (160,160,3)

    // workspace carve (256B aligned), ~28 MB
    char* p = (char*)d_ws;
    auto alloc = [&](size_t bytes) { void* r = (void*)p; p += (bytes + 255) & ~(size_t)255; return r; };
    float*   meanp = (float*)alloc(4);
    float*   mval  = (float*)alloc(MAXN * 4);
    float2*  Wf    = (float2*)alloc((size_t)NP * 8);
    float2*  UH    = (float2*)alloc((size_t)6 * NP * 8);   // U2 | Hb
    float2*  Td    = (float2*)alloc((size_t)6 * NP * 8);
    float2*  EF    = (float2*)alloc((size_t)6 * NP * 8);   // FU | FH
    float2*  U3    = (float2*)alloc((size_t)3 * NP * 8);
    double2* spart = (double2*)alloc(64 * 16);
    unsigned short* P4   = (unsigned short*)alloc((size_t)2 * P4_SIDE * 2);
    unsigned short* IMG2 = (unsigned short*)alloc((size_t)2 * IMG_SIDE * 2);
    float*   PART  = (float*)alloc((size_t)48 * RESO * RESO * 4);

    float2* U2 = UH;
    float2* Hb = UH + (size_t)3 * NP;

    // exact python-f64 scalar path
    double dx = 0.002 / 255.0;
    double Lx = dx * 255.0;
    double ap = (Lx / 2.0) * 0.1 + 1e-7;
    float ap_f = (float)ap;

    double xstart = -(Lx / 2.0);
    double xstop  =  Lx / 2.0;
    double xstep  = (xstop - xstart) / 254.0;
    double fstart = -1.0 / (2.0 * dx);
    double fstop  =  1.0 / (2.0 * dx);
    double fstep  = (fstop - fstart) / 254.0;

    k_mleaf<<<(PW.nNode + 255) / 256, 256, 0, stream>>>(depth, mval);
    k_mtree<<<1, 256, 0, stream>>>(depth, mval, meanp);
    int gprep = (4 * NP + IMG_SIDE + 255) / 256;   // 3201
    k_prep<<<gprep, 256, 0, stream>>>(image, IMG2, Wf, U2, Hb, meanp,
                                      xstart, xstep, xstop,
                                      fstart, fstep, fstop, ap_f);

    dim3 bb(256);
    k_cgemm<<<dim3(8, 16, 6), bb, 0, stream>>>(Wf, 0, UH, nullptr, NP, Td, 0, 0, 1.0f);
    k_cgemm<<<dim3(8, 16, 6), bb, 0, stream>>>(Td, NP, Wf, nullptr, 0, EF, 0, 0, 1.0f);
    k_cgemm<<<dim3(8, 16, 3), bb, 0, stream>>>(Wf, 0, EF + (size_t)3 * NP, EF, NP,
                                               Td, 1, 0, 1.0f / 255.0f);
    k_cgemm<<<dim3(8, 16, 3), bb, 0, stream>>>(Td, NP, Wf, nullptr, 0, U3, 0, 1,
                                               1.0f / 255.0f);

    k_sred<<<64, 256, 0, stream>>>(U3, spart);
    k_p4<<<(P4_SIDE + 255) / 256, 256, 0, stream>>>(U3, spart, P4);

    k_conv<<<dim3(5, 5, 48), 256, 0, stream>>>(IMG2, P4, PART);
    k_out<<<300, 256, 0, stream>>>(PART, out);
}

// Round 15
// 237.640 us; speedup vs baseline: 1.2983x; 1.0503x over previous
//
#include <hip/hip_runtime.h>
#include <hip/hip_bf16.h>
#include <math.h>

// ---------------------------------------------------------------------------
// MjCambrianOptics. Correctness-critical (R7-validated, DO NOT TOUCH):
//   * mean(depth) = numpy BUFFERED reduce: seed a[0], then sequential
//     += pairwise_sum(8192-chunk), 128-leaf/8-acc recursion.
//   * ki = fl32(2pi)/fl32(wl) f32 divide; linspace f64-cast; th/ph op order.
// R11: conv -> MFMA (banded-Toeplitz implicit GEMM, split-bf16 hi/lo).
// R17: sliding-window P4 => coalesced A-loads. 162->82 us (CONFIRMED).
// R18: two j-tiles/block (A reuse). 82->55.6.
// R19: more cgemm blocks (64->128/plane) won ~19 us; (256,4) k_conv spilled.
// R20: (256,2) + 16x32 cgemm 128-blocks/plane. tot 252.7.
// R21/R22: cgemm intensity tweaks regressed; parallelism is cgemm's lever.
// R25: k_conv 2x2 tiles (12 MFMA/A-frag), k_sfin fused into k_p4. 249.6.
// R26: cgemm 16x16 tiles, 1 output/thread, grid (16,16,z) = 256 blocks/plane
//      (z=6 -> 6 blocks/CU). Same per-output kt/kk order -> bit-identical.
// ---------------------------------------------------------------------------

constexpr int M   = 255;
constexpr int NP  = M * M;        // 65025
constexpr int RESO = 160;

// IMG2 (padded bf16 image, hi|lo): [side][ch][row 0..415][col 0..447]
constexpr int IMG_ROWS = 416, IMG_COLS = 448;
constexpr int IMG_CH   = IMG_ROWS * IMG_COLS;      // 186368
constexpr int IMG_SIDE = 3 * IMG_CH;               // 559104
// P4 sliding-window table (bf16 hi|lo): [side][ch][di 0..255][u 0..303][t 0..7]
// entry (di,u,t) = psf[di][u-16+t], zero-padded outside [0,M)
constexpr int P4_DI   = 304 * 8;                   // 2432 shorts per di
constexpr int P4_CH   = 256 * P4_DI;               // 622592
constexpr int P4_SIDE = 3 * P4_CH;                 // 1867776

typedef __attribute__((ext_vector_type(8))) short short8;
typedef __attribute__((ext_vector_type(4))) float f32x4;

__device__ __forceinline__ unsigned short f2bf(float f) {
    unsigned int u = __float_as_uint(f);
    unsigned int r = (u + 0x7fffu + ((u >> 16) & 1u)) >> 16;
    return (unsigned short)r;
}
__device__ __forceinline__ float bf2f(unsigned short h) {
    return __uint_as_float(((unsigned int)h) << 16);
}

// ---------------- numpy buffered-reduce pairwise forest (compile-time) ------
constexpr int MAXN = 1100;
struct PWForest {
    int kind[MAXN];
    int off[MAXN], len[MAXN];
    int li[MAXN], ri[MAXN];
    int lvl[MAXN];
    int nNode, nLeaf, maxLvl;
    int roots[16], nRoots;
};
constexpr int pwf_build(PWForest& T, int o, int n) {
    if (n <= 128) {
        int id = T.nNode++;
        T.kind[id] = 0; T.off[id] = o; T.len[id] = n;
        T.lvl[id] = 0; T.nLeaf++;
        return id;
    }
    int n2 = (n / 2) - ((n / 2) % 8);
    int a = pwf_build(T, o, n2);
    int b = pwf_build(T, o + n2, n - n2);
    int id = T.nNode++;
    T.kind[id] = 1; T.li[id] = a; T.ri[id] = b;
    int l = (T.lvl[a] > T.lvl[b] ? T.lvl[a] : T.lvl[b]) + 1;
    T.lvl[id] = l; if (l > T.maxLvl) T.maxLvl = l;
    return id;
}
constexpr PWForest pwf_make() {
    PWForest T{};
    int pos = 1, rem = NP - 1;            // reduce seeds with a[0]
    while (rem > 0) {
        int c = rem > 8192 ? 8192 : rem;  // nditer buffer = 8192 elements
        T.roots[T.nRoots++] = pwf_build(T, pos, c);
        pos += c; rem -= c;
    }
    return T;
}
constexpr PWForest PW = pwf_make();
static_assert(PW.nNode <= MAXN, "forest overflow");
static_assert(PW.nRoots == 8, "chunk count");

// leaves are independent: one THREAD per node id, exact per-leaf arithmetic
__global__ void k_mleaf(const float* __restrict__ depth, float* __restrict__ val) {
    int id = blockIdx.x * 256 + threadIdx.x;
    if (id >= PW.nNode || PW.kind[id] != 0) return;
    const float* a = depth + PW.off[id];
    int n = PW.len[id];
    float r0 = a[0], r1 = a[1], r2 = a[2], r3 = a[3];
    float r4 = a[4], r5 = a[5], r6 = a[6], r7 = a[7];
    int lim = n - (n % 8);
    int i = 8;
    for (; i < lim; i += 8) {
        r0 += a[i + 0]; r1 += a[i + 1]; r2 += a[i + 2]; r3 += a[i + 3];
        r4 += a[i + 4]; r5 += a[i + 5]; r6 += a[i + 6]; r7 += a[i + 7];
    }
    float res = ((r0 + r1) + (r2 + r3)) + ((r4 + r5) + (r6 + r7));
    for (; i < n; ++i) res += a[i];
    val[id] = res;
}

// internal levels + root chain, single block (exact same order as before)
__global__ void k_mtree(const float* __restrict__ depth, float* __restrict__ val,
                        float* __restrict__ meanp) {
    int tid = threadIdx.x;
    for (int l = 1; l <= PW.maxLvl; ++l) {
        for (int id = tid; id < PW.nNode; id += 256)
            if (PW.kind[id] == 1 && PW.lvl[id] == l)
                val[id] = val[PW.li[id]] + val[PW.ri[id]];
        __syncthreads();
    }
    if (tid == 0) {
        float io1 = depth[0];
        for (int r = 0; r < PW.nRoots; ++r)
            io1 = io1 + val[PW.roots[r]];
        meanp[0] = io1 / 65025.0f;
    }
}

// ---------------- prep: u2H fields + DFT W + padded bf16 image --------------
__global__ void k_prep(const float* __restrict__ img, unsigned short* __restrict__ IMG2,
                       float2* __restrict__ W,
                       float2* __restrict__ U2, float2* __restrict__ Hb,
                       const float* __restrict__ meanp,
                       double xstart, double xstep, double xstop,
                       double fstart, double fstep, double fstop,
                       float ap_f) {
#pragma clang fp contract(off)
    int idx = blockIdx.x * 256 + threadIdx.x;
    if (idx < 3 * NP) {
        int c = idx / NP, ij = idx % NP, i = ij / M, j = ij % M;
        const float wls[3] = {6.1e-07f, 5.3e-07f, 4.7e-07f};
        float wl = wls[c];
        float ki = ((float)6.283185307179586) / wl;
        float d  = meanp[0];
        float d2 = d * d;

        float x  = (i == 254) ? (float)xstop : (float)((double)i * xstep + xstart);
        float y  = (j == 254) ? (float)xstop : (float)((double)j * xstep + xstart);
        float fx = (i == 254) ? (float)fstop : (float)((double)i * fstep + fstart);
        float fy = (j == 254) ? (float)fstop : (float)((double)j * fstep + fstart);

        float xx = x * x, yy = y * y;
        float X1Y1 = xx + yy;

        float s  = sqrtf(X1Y1 + d2);
        float th = ki * s;
        float A  = (sqrtf(X1Y1) / ap_f <= 1.0f) ? 1.0f : 0.0f;
        float2 u2v;
        if (A != 0.0f) u2v = make_float2((float)cos((double)th), (float)sin((double)th));
        else           u2v = make_float2(0.0f, 0.0f);

        float a = wl * fx, b = wl * fy;
        float arg = (1.0f - a * a) - b * b;
        float FXY = sqrtf(fmaxf(arg, 0.0f));
        float Hv  = (sqrtf(fx * fx + fy * fy) < (1.0f / wl)) ? 1.0f : 0.0f;
        float kd  = ki * d;
        float ph  = kd * FXY;
        float cph = (float)cos((double)ph), sph = (float)sin((double)ph);
        float2 hv = make_float2(Hv * cph, Hv * sph);

        U2[idx] = u2v;
        Hb[idx] = hv;
        return;
    }
    if (idx < 4 * NP) {
        int e = idx - 3 * NP;
        int n = e / M, k = e % M;
        int m = (n * k) % M;
        double ang = -2.0 * 3.14159265358979323846 * (double)m / 255.0;
        W[e] = make_float2((float)cos(ang), (float)sin(ang));
        return;
    }
    int e = idx - 4 * NP;
    if (e >= IMG_SIDE) return;
    int ch = e / IMG_CH, rem = e % IMG_CH;
    int prow = rem / IMG_COLS, pcol = rem % IMG_COLS;
    int a = prow - 80, b = pcol - 80;
    float v = 0.0f;
    if (a >= 0 && a < M && b >= 0 && b < M) v = img[(a * M + b) * 3 + ch];
    unsigned short hi = f2bf(v);
    unsigned short lo = f2bf(v - bf2f(hi));
    IMG2[e] = hi;
    IMG2[IMG_SIDE + e] = lo;
}

// ---------------- batched f32 complex GEMM, 16x16 tile, 1/thread ------------
// R26: 256 blocks/plane (was 128). Per-output K accumulation sequence is
// unchanged (same kt/kk order, same FMA expressions) -> bit-identical.
// One-kt-ahead register prefetch (1 A + 1 B float2 scalar).
#define CG_LOAD(KT, VA, WB) { \
    int k0_ = (KT) * 16; \
    { int r_ = threadIdx.x >> 4, c_ = threadIdx.x & 15; \
      int gi_ = i0 + r_, gk_ = k0_ + c_; \
      VA = (gi_ < M && gk_ < M) ? Ab[gi_ * M + gk_] : make_float2(0.f, 0.f); \
      if (conjA) VA.y = -VA.y; } \
    { int r2_ = threadIdx.x >> 4, c2_ = threadIdx.x & 15; \
      int gk2_ = k0_ + r2_, gj_ = j0 + c2_; \
      WB = make_float2(0.f, 0.f); \
      if (gk2_ < M && gj_ < M) { \
          WB = Bb[gk2_ * M + gj_]; \
          if (B2b) { float2 z_ = B2b[gk2_ * M + gj_]; \
              WB = make_float2(WB.x * z_.x - WB.y * z_.y, WB.x * z_.y + WB.y * z_.x); } \
      } \
      if (conjB) WB.y = -WB.y; } }

__global__ __launch_bounds__(256)
void k_cgemm(const float2* __restrict__ A, int aBatch,
             const float2* __restrict__ B, const float2* __restrict__ B2,
             int bBatch, float2* __restrict__ C,
             int conjA, int conjB, float scale) {
    __shared__ float2 As[16][17];
    __shared__ float2 Bs[16][17];
    int c = blockIdx.z;
    int tx = threadIdx.x & 15, ty = threadIdx.x >> 4;
    int i0 = blockIdx.y * 16, j0 = blockIdx.x * 16;
    const float2* Ab = A + (size_t)c * aBatch;
    const float2* Bb = B + (size_t)c * bBatch;
    const float2* B2b = B2 ? (B2 + (size_t)c * bBatch) : nullptr;
    float2 a00 = {0,0};

    int wrA = threadIdx.x >> 4, wcA = threadIdx.x & 15;

    float2 vA, wB;                      // current kt staging values
    float2 nA, nB;                      // next kt
    CG_LOAD(0, vA, wB)

    for (int kt = 0; kt < 16; ++kt) {
        As[wrA][wcA] = vA;
        Bs[wrA][wcA] = wB;
        if (kt < 15) { CG_LOAD(kt + 1, nA, nB) }
        __syncthreads();
#pragma unroll
        for (int kk = 0; kk < 16; ++kk) {
            float2 p = As[ty][kk];
            float2 u = Bs[kk][tx];
            a00.x += p.x * u.x - p.y * u.y;  a00.y += p.x * u.y + p.y * u.x;
        }
        __syncthreads();
        vA = nA; wB = nB;
    }
    float2* Cb = C + (size_t)c * NP;
    int gi = i0 + ty;
    int gj = j0 + tx;
    if (gi < M && gj < M) Cb[gi * M + gj] = make_float2(a00.x * scale, a00.y * scale);
}

// ---------------- S = sum u3^2 (f64 accumulate over f32 u3) ----------------
__global__ void k_sred(const float2* __restrict__ U3, double2* __restrict__ spart) {
    __shared__ double sx[256], sy[256];
    int t = threadIdx.x;
    double ax = 0.0, ay = 0.0;
    for (int i = blockIdx.x * 256 + t; i < 3 * NP; i += 64 * 256) {
        double zx = (double)U3[i].x, zy = (double)U3[i].y;
        ax += zx * zx - zy * zy;
        ay += 2.0 * zx * zy;
    }
    sx[t] = ax; sy[t] = ay;
    __syncthreads();
    for (int w = 128; w > 0; w >>= 1) {
        if (t < w) { sx[t] += sx[t + w]; sy[t] += sy[t + w]; }
        __syncthreads();
    }
    if (t == 0) spart[blockIdx.x] = make_double2(sx[0], sy[0]);
}

// ---------------- psf -> P4 sliding-window bf16 hi/lo table -----------------
// P4[ch][di][u][t] = psf[di][u-16+t]  (u 0..303, t 0..7, zero-padded)
// R25: spart finalization fused in (lane 0 per block, exact same sum order).
__global__ void k_p4(const float2* __restrict__ U3, const double2* __restrict__ spart,
                     unsigned short* __restrict__ P4) {
    __shared__ double sh[3];
    if (threadIdx.x == 0) {
        double rx = 0.0, ry = 0.0;
        for (int i = 0; i < 64; ++i) { rx += spart[i].x; ry += spart[i].y; }
        double dsx_ = rx + 1e-7, dsy_ = ry;      // same association as before
        sh[0] = dsx_; sh[1] = dsy_;
        sh[2] = 1.0 / (dsx_ * dsx_ + dsy_ * dsy_);
    }
    __syncthreads();
    int idx = blockIdx.x * 256 + threadIdx.x;
    if (idx >= P4_SIDE) return;
    double dsx = sh[0], dsy = sh[1], inv = sh[2];
    int ch = idx / P4_CH, rem = idx % P4_CH;
    int di = rem / P4_DI, rem2 = rem % P4_DI;
    int u = rem2 / 8, t = rem2 % 8;
    int p = u - 16 + t;
    float v = 0.0f;
    if (di < M && p >= 0 && p < M) {
        float2 zf = U3[(ch * M + di) * M + p];
        double zx = (double)zf.x, zy = (double)zf.y;
        double zr = zx * zx - zy * zy;
        double zi = 2.0 * zx * zy;
        v = (float)((zr * dsx + zi * dsy) * inv);
    }
    unsigned short hi = f2bf(v);
    unsigned short lo = f2bf(v - bf2f(hi));
    P4[idx] = hi;
    P4[P4_SIDE + idx] = lo;
}

// ---------------- MFMA conv: banded-Toeplitz implicit GEMM ------------------
// R25: 4 waves, FOUR 16x16 output tiles (i0/i0+16 x j0/j0+16), one (ch,
// 16-di chunk). A registers (independent of i AND j) feed 12 MFMA per
// fragment. Image tile 47 rows x 304 cols (hi+lo) in stride-312 LDS
// (57.3 KB). One-dloc-ahead A prefetch with sched_barrier fences;
// launch_bounds(256,2) (R19: needs the 256-VGPR budget).
// R21 lesson: LDS bank conflicts here are HIDDEN — do not swizzle.
// A[m=lane&15][k=8q+t] = psf[di][32c + 8q + t - m]   (window u = su0+32c)
// B[k=8q+t][n=lane&15] = img[iT+n+di-80][jT-80+32c+8q+t], iT=i0|i0+16, jT=j0|j0+16
// D: row(=m/j) = 4q+reg, col(=n/i) = lane&15.
constexpr int LDS_STRIDE = 312;    // shorts; 624 B rows, 16B aligned

#define SB __builtin_amdgcn_sched_barrier(0);

#define REP9(OP) OP(0) OP(1) OP(2) OP(3) OP(4) OP(5) OP(6) OP(7) OP(8)

#define DECLA(i) short8 Ah_##i, Al_##i;
#define DECLB(i) short8 Bh_##i, Bl_##i;

#define LDA(i) Ah_##i = *(const short8*)(prH + 256 * i); \
               Al_##i = *(const short8*)(prL + 256 * i);
#define LDB(i) Bh_##i = *(const short8*)(prH + 256 * i); \
               Bl_##i = *(const short8*)(prL + 256 * i);
#define LOADA(dl) { const unsigned short* prH = pHc + (size_t)(d0 + (dl)) * P4_DI + aoff; \
                    const unsigned short* prL = pLc + (size_t)(d0 + (dl)) * P4_DI + aoff; \
                    REP9(LDA) }
#define LOADB(dl) { const unsigned short* prH = pHc + (size_t)(d0 + (dl)) * P4_DI + aoff; \
                    const unsigned short* prL = pLc + (size_t)(d0 + (dl)) * P4_DI + aoff; \
                    REP9(LDB) }

#define CMBODY(AH, AL) { \
    short8 bh00 = *(const short8*)&ldsI[0][rrow][colb]; \
    short8 bl00 = *(const short8*)&ldsI[1][rrow][colb]; \
    short8 bh01 = *(const short8*)&ldsI[0][rrow][colb + 16]; \
    short8 bl01 = *(const short8*)&ldsI[1][rrow][colb + 16]; \
    short8 bh10 = *(const short8*)&ldsI[0][rrow + 16][colb]; \
    short8 bl10 = *(const short8*)&ldsI[1][rrow + 16][colb]; \
    short8 bh11 = *(const short8*)&ldsI[0][rrow + 16][colb + 16]; \
    short8 bl11 = *(const short8*)&ldsI[1][rrow + 16][colb + 16]; \
    aHH00 = __builtin_amdgcn_mfma_f32_16x16x32_bf16(AH, bh00, aHH00, 0, 0, 0); \
    aHL00 = __builtin_amdgcn_mfma_f32_16x16x32_bf16(AH, bl00, aHL00, 0, 0, 0); \
    aLH00 = __builtin_amdgcn_mfma_f32_16x16x32_bf16(AL, bh00, aLH00, 0, 0, 0); \
    aHH01 = __builtin_amdgcn_mfma_f32_16x16x32_bf16(AH, bh01, aHH01, 0, 0, 0); \
    aHL01 = __builtin_amdgcn_mfma_f32_16x16x32_bf16(AH, bl01, aHL01, 0, 0, 0); \
    aLH01 = __builtin_amdgcn_mfma_f32_16x16x32_bf16(AL, bh01, aLH01, 0, 0, 0); \
    aHH10 = __builtin_amdgcn_mfma_f32_16x16x32_bf16(AH, bh10, aHH10, 0, 0, 0); \
    aHL10 = __builtin_amdgcn_mfma_f32_16x16x32_bf16(AH, bl10, aHL10, 0, 0, 0); \
    aLH10 = __builtin_amdgcn_mfma_f32_16x16x32_bf16(AL, bh10, aLH10, 0, 0, 0); \
    aHH11 = __builtin_amdgcn_mfma_f32_16x16x32_bf16(AH, bh11, aHH11, 0, 0, 0); \
    aHL11 = __builtin_amdgcn_mfma_f32_16x16x32_bf16(AH, bl11, aHL11, 0, 0, 0); \
    aLH11 = __builtin_amdgcn_mfma_f32_16x16x32_bf16(AL, bh11, aLH11, 0, 0, 0); }

#define CMA(i) { int colb = 32 * i + 8 * q; CMBODY(Ah_##i, Al_##i) }
#define CMB(i) { int colb = 32 * i + 8 * q; CMBODY(Bh_##i, Bl_##i) }
#define COMPA(dl) { int rrow = ln + (dl); REP9(CMA) }
#define COMPB(dl) { int rrow = ln + (dl); REP9(CMB) }

__global__ __launch_bounds__(256, 2)
void k_conv(const unsigned short* __restrict__ IMG2,
            const unsigned short* __restrict__ P4,
            float* __restrict__ PART) {
    __shared__ __align__(16) unsigned short ldsI[2][47][LDS_STRIDE];

    int tid  = threadIdx.x;
    int w    = tid >> 6;           // wave 0..3
    int lane = tid & 63;
    int ln   = lane & 15;          // m for A, n for B/C-col
    int q    = lane >> 4;          // 0..3
    int j0 = blockIdx.x * 32;      // j-tiles j0, j0+16
    int i0 = blockIdx.y * 32;      // i-tiles i0, i0+16
    int bz = blockIdx.z;           // ch*16 + chunk
    int ch = bz >> 4, chunk = bz & 15;
    int d0 = chunk << 4;

    const unsigned short* imgH = IMG2 + ch * IMG_CH;
    const unsigned short* imgL = imgH + IMG_SIDE;
    const unsigned short* pHc  = P4 + ch * P4_CH;
    const unsigned short* pLc  = pHc + P4_SIDE;

    // sliding-window index: u = su0 + 32*cc, su0 = 16 + 8q - ln in 1..40
    int su0  = 16 + 8 * q - ln;
    int aoff = su0 * 8;                    // shorts; + 256 per cc step

    f32x4 aHH00 = {0,0,0,0}, aHL00 = {0,0,0,0}, aLH00 = {0,0,0,0};
    f32x4 aHH01 = {0,0,0,0}, aHL01 = {0,0,0,0}, aLH01 = {0,0,0,0};
    f32x4 aHH10 = {0,0,0,0}, aHL10 = {0,0,0,0}, aLH10 = {0,0,0,0};
    f32x4 aHH11 = {0,0,0,0}, aHL11 = {0,0,0,0}, aLH11 = {0,0,0,0};

    REP9(DECLA)
    REP9(DECLB)

    int dbase = 4 * w;
    LOADA(dbase + 0)               // in flight during staging

    // ---- stage image tile: rows i0+d0 .. +46, cols j0 .. j0+303, hi+lo ----
    int row0 = i0 + d0;
    for (int idx = tid; idx < 2 * 47 * 38; idx += 256) {
        int plane = idx / (47 * 38);
        int rem = idx - plane * (47 * 38);
        int r = rem / 38, c = rem - r * 38;
        const unsigned short* src =
            (plane ? imgL : imgH) + (size_t)(row0 + r) * IMG_COLS + j0 + c * 8;
        *(short8*)&ldsI[plane][r][c * 8] = *(const short8*)src;
    }
    __syncthreads();

    LOADB(dbase + 1)
    SB
    COMPA(dbase + 0)
    SB
    LOADA(dbase + 2)
    SB
    COMPB(dbase + 1)
    SB
    LOADB(dbase + 3)
    SB
    COMPA(dbase + 2)
    SB
    COMPB(dbase + 3)

    // ---- combine the three precision terms, then reduce across the 4 waves
    f32x4 tot00, tot01, tot10, tot11;
#pragma unroll
    for (int r = 0; r < 4; ++r) {
        tot00[r] = aHH00[r] + aHL00[r] + aLH00[r];
        tot01[r] = aHH01[r] + aHL01[r] + aLH01[r];
        tot10[r] = aHH10[r] + aHL10[r] + aLH10[r];
        tot11[r] = aHH11[r] + aHL11[r] + aLH11[r];
    }

    __syncthreads();                       // everyone done reading image LDS
    float* red = (float*)&ldsI[0][0][0];
    if (w) {
#pragma unroll
        for (int r = 0; r < 4; ++r) {
            int base = ((w - 1) * 64 + lane) * 16;
            red[base + r]      = tot00[r];
            red[base + 4 + r]  = tot01[r];
            red[base + 8 + r]  = tot10[r];
            red[base + 12 + r] = tot11[r];
        }
    }
    __syncthreads();
    if (w == 0) {
#pragma unroll
        for (int wv = 0; wv < 3; ++wv)
#pragma unroll
            for (int r = 0; r < 4; ++r) {
                int base = (wv * 64 + lane) * 16;
                tot00[r] += red[base + r];
                tot01[r] += red[base + 4 + r];
                tot10[r] += red[base + 8 + r];
                tot11[r] += red[base + 12 + r];
            }
        // D row = 4q+reg -> j = jT+4q+reg ; D col = ln -> i = iT+ln
        float* op0 = PART + (size_t)bz * (RESO * RESO) + (i0 + ln) * RESO + j0 + 4 * q;
        float* op1 = PART + (size_t)bz * (RESO * RESO) + (i0 + 16 + ln) * RESO + j0 + 4 * q;
        float4 o;
        o.x = tot00[0]; o.y = tot00[1]; o.z = tot00[2]; o.w = tot00[3];
        *(float4*)op0 = o;
        o.x = tot01[0]; o.y = tot01[1]; o.z = tot01[2]; o.w = tot01[3];
        *(float4*)(op0 + 16) = o;
        o.x = tot10[0]; o.y = tot10[1]; o.z = tot10[2]; o.w = tot10[3];
        *(float4*)op1 = o;
        o.x = tot11[0]; o.y = tot11[1]; o.z = tot11[2]; o.w = tot11[3];
        *(float4*)(op1 + 16) = o;
    }
}

// ---------------- reduce partials + clip + layout (i,j,c) ----------------
__global__ void k_out(const float* __restrict__ PART, float* __restrict__ out) {
    int idx = blockIdx.x * 256 + threadIdx.x;
    if (idx >= 3 * RESO * RESO) return;
    int c = idx / (RESO * RESO), ij = idx % (RESO * RESO);
    float s = 0.0f;
    for (int kz = 0; kz < 16; ++kz)
        s += PART[(size_t)(c * 16 + kz) * (RESO * RESO) + ij];
    s = fminf(fmaxf(s, 0.0f), 1.0f);
    int i = ij / RESO, j = ij % RESO;
    out[(i * RESO + j) * 3 + c] = s;
}

// ---------------------------------------------------------------------------
extern "C" void kernel_launch(void* const* d_in, const int* in_sizes, int n_in,
                              void* d_out, int out_size, void* d_ws, size_t ws_size,
                              hipStream_t stream) {
    const float* image = (const float*)d_in[0];   // (255,255,3)
    const float* depth = (const float*)d_in[1];   // (255,255)
    float* out = (float*)d_out;                   // (160,160,3)

    // workspace carve (256B aligned), ~28 MB
    char* p = (char*)d_ws;
    auto alloc = [&](size_t bytes) { void* r = (void*)p; p += (bytes + 255) & ~(size_t)255; return r; };
    float*   meanp = (float*)alloc(4);
    float*   mval  = (float*)alloc(MAXN * 4);
    float2*  Wf    = (float2*)alloc((size_t)NP * 8);
    float2*  UH    = (float2*)alloc((size_t)6 * NP * 8);   // U2 | Hb
    float2*  Td    = (float2*)alloc((size_t)6 * NP * 8);
    float2*  EF    = (float2*)alloc((size_t)6 * NP * 8);   // FU | FH
    float2*  U3    = (float2*)alloc((size_t)3 * NP * 8);
    double2* spart = (double2*)alloc(64 * 16);
    unsigned short* P4   = (unsigned short*)alloc((size_t)2 * P4_SIDE * 2);
    unsigned short* IMG2 = (unsigned short*)alloc((size_t)2 * IMG_SIDE * 2);
    float*   PART  = (float*)alloc((size_t)48 * RESO * RESO * 4);

    float2* U2 = UH;
    float2* Hb = UH + (size_t)3 * NP;

    // exact python-f64 scalar path
    double dx = 0.002 / 255.0;
    double Lx = dx * 255.0;
    double ap = (Lx / 2.0) * 0.1 + 1e-7;
    float ap_f = (float)ap;

    double xstart = -(Lx / 2.0);
    double xstop  =  Lx / 2.0;
    double xstep  = (xstop - xstart) / 254.0;
    double fstart = -1.0 / (2.0 * dx);
    double fstop  =  1.0 / (2.0 * dx);
    double fstep  = (fstop - fstart) / 254.0;

    k_mleaf<<<(PW.nNode + 255) / 256, 256, 0, stream>>>(depth, mval);
    k_mtree<<<1, 256, 0, stream>>>(depth, mval, meanp);
    int gprep = (4 * NP + IMG_SIDE + 255) / 256;   // 3201
    k_prep<<<gprep, 256, 0, stream>>>(image, IMG2, Wf, U2, Hb, meanp,
                                      xstart, xstep, xstop,
                                      fstart, fstep, fstop, ap_f);

    dim3 bb(256);
    k_cgemm<<<dim3(16, 16, 6), bb, 0, stream>>>(Wf, 0, UH, nullptr, NP, Td, 0, 0, 1.0f);
    k_cgemm<<<dim3(16, 16, 6), bb, 0, stream>>>(Td, NP, Wf, nullptr, 0, EF, 0, 0, 1.0f);
    k_cgemm<<<dim3(16, 16, 3), bb, 0, stream>>>(Wf, 0, EF + (size_t)3 * NP, EF, NP,
                                                Td, 1, 0, 1.0f / 255.0f);
    k_cgemm<<<dim3(16, 16, 3), bb, 0, stream>>>(Td, NP, Wf, nullptr, 0, U3, 0, 1,
                                                1.0f / 255.0f);

    k_sred<<<64, 256, 0, stream>>>(U3, spart);
    k_p4<<<(P4_SIDE + 255) / 256, 256, 0, stream>>>(U3, spart, P4);

    k_conv<<<dim3(5, 5, 48), 256, 0, stream>>>(IMG2, P4, PART);
    k_out<<<300, 256, 0, stream>>>(PART, out);
}